// Round 5
// baseline (228.558 us; speedup 1.0000x reference)
//
#include <hip/hip_runtime.h>
#include <hip/hip_bf16.h>
#include <stdint.h>

typedef __bf16 bf16x8 __attribute__((ext_vector_type(8)));
typedef _Float16 f16x8 __attribute__((ext_vector_type(8)));
typedef float  f32x4  __attribute__((ext_vector_type(4)));

#define RATIO 0.08838834764831845f
#define EPSV  1e-4f

#define GLOBAL_AS __attribute__((address_space(1)))
#define LDS_AS    __attribute__((address_space(3)))

static __device__ __forceinline__ void gload16(const void* g, void* l) {
  __builtin_amdgcn_global_load_lds((GLOBAL_AS const void*)g, (LDS_AS void*)l, 16, 0, 0);
}

// monotonic float<->uint key for exact atomicMax
static __device__ __forceinline__ unsigned fkey(float f) {
  unsigned b = __float_as_uint(f);
  return (b & 0x80000000u) ? ~b : (b | 0x80000000u);
}
static __device__ __forceinline__ float funkey(unsigned k) {
  unsigned b = (k & 0x80000000u) ? (k & 0x7FFFFFFFu) : ~k;
  return __uint_as_float(b);
}

// ---------------- workspace layout (bytes) ----------------
static constexpr size_t OFF_XB    = 0;                        // 16384*128*2
static constexpr size_t OFF_WCAT  = OFF_XB    + 4194304;
static constexpr size_t OFF_MQ    = OFF_WCAT  + 98304;
static constexpr size_t OFF_MK    = OFF_MQ    + 262144;
static constexpr size_t OFF_BCAT  = OFF_MK    + 262144;
static constexpr size_t OFF_BQF   = OFF_BCAT  + 2048;
static constexpr size_t OFF_BKF   = OFF_BQF   + 4096;
static constexpr size_t OFF_Y     = OFF_BKF   + 4096;         // 16384*384*4
static constexpr size_t OFF_QF    = OFF_Y     + 25165824;     // 8*2048*1024*2
static constexpr size_t OFF_KF    = OFF_QF    + 33554432;
static constexpr size_t OFF_KFT   = OFF_KF    + 33554432;
static constexpr size_t OFF_VFT   = OFF_KFT   + 33554432;     // 8*128*2048*2
static constexpr size_t OFF_KMAXI = OFF_VFT   + 4194304;      // 64*4 (pad 1024)
static constexpr size_t OFF_KSUMP = OFF_KMAXI + 1024;         // 4*8*1024*4
static constexpr size_t OFF_EK    = OFF_KSUMP + 131072;       // 16384*1024? no: 8*16384*128*2
static constexpr size_t OFF_CTXP  = OFF_EK    + 33554432;     // 4*8*128*1024*4
static constexpr size_t OFF_CTXT  = OFF_CTXP  + 16777216;     // 8*128*1024*2
static constexpr size_t WS_NEED   = OFF_CTXT  + 2097152;

// ---------------- shared NT-GEMM core: C(128x128) = A(tm:,*) * B(tn:,*)^T ----
static __device__ __forceinline__ void gemm_core(
    const __hip_bfloat16* __restrict__ A, const __hip_bfloat16* __restrict__ B,
    int lda, int ldb, int K, int tm, int tn,
    __bf16* As, __bf16* Bs, f32x4 acc[4][4]) {
  const int t    = threadIdx.x;
  const int w    = t >> 6;
  const int lane = t & 63;
  const int m_off = (w >> 1) << 6;
  const int n_off = (w & 1) << 6;
  const int r0 = t >> 2;
  const int kk = (t & 3) << 3;
  char* Asb = (char*)As + (w << 10);
  char* Bsb = (char*)Bs + (w << 10);
  const int frow = lane & 15;
  const int koff = (lane >> 4) << 3;
  for (int k0 = 0; k0 < K; k0 += 32) {
    const __hip_bfloat16* Ag = A + (size_t)(tm + r0) * lda + (k0 + kk);
    const __hip_bfloat16* Bg = B + (size_t)(tn + r0) * ldb + (k0 + kk);
    gload16(Ag, Asb);
    gload16(Ag + (size_t)64 * lda, Asb + 4096);
    gload16(Bg, Bsb);
    gload16(Bg + (size_t)64 * ldb, Bsb + 4096);
    __syncthreads();
    bf16x8 af[4], bfr[4];
#pragma unroll
    for (int mi = 0; mi < 4; ++mi)
      af[mi] = *(const bf16x8*)(As + ((m_off + mi * 16 + frow) << 5) + koff);
#pragma unroll
    for (int ni = 0; ni < 4; ++ni)
      bfr[ni] = *(const bf16x8*)(Bs + ((n_off + ni * 16 + frow) << 5) + koff);
#pragma unroll
    for (int mi = 0; mi < 4; ++mi)
#pragma unroll
      for (int ni = 0; ni < 4; ++ni)
        acc[mi][ni] = __builtin_amdgcn_mfma_f32_16x16x32_bf16(af[mi], bfr[ni], acc[mi][ni], 0, 0, 0);
    __syncthreads();
  }
}

#define ZERO_ACC(acc) do {                                   \
  _Pragma("unroll") for (int a_ = 0; a_ < 4; ++a_)           \
  _Pragma("unroll") for (int b_ = 0; b_ < 4; ++b_)           \
    acc[a_][b_] = (f32x4){0.f, 0.f, 0.f, 0.f};               \
} while (0)

// ---------------- fused prep kernel ----------------
__global__ void k_prep(const float* __restrict__ x,
                       const float* __restrict__ Wq, const float* __restrict__ bq,
                       const float* __restrict__ Wk, const float* __restrict__ bk,
                       const float* __restrict__ Wv, const float* __restrict__ bv,
                       const float* __restrict__ proj,
                       __hip_bfloat16* __restrict__ xb,
                       __hip_bfloat16* __restrict__ Wcat, float* __restrict__ bcat,
                       __hip_bfloat16* __restrict__ Mq, __hip_bfloat16* __restrict__ Mk,
                       float* __restrict__ bqf, float* __restrict__ bkf,
                       unsigned* __restrict__ kmaxI) {
  const int b = blockIdx.x, t = threadIdx.x;
  { // convx: all 2048 blocks
    int i = (b * 256 + t) * 4;
    f32x4 v = *(const f32x4*)(x + i);
#pragma unroll
    for (int j = 0; j < 4; ++j) xb[i + j] = __float2bfloat16(v[j]);
  }
  if (b == 0 && t < 64) kmaxI[t] = 0u;
  if (b < 1024) { // prepM
    int i = b * 256 + t;
    {
      int which = i >> 17;
      int rem = i & 131071;
      int hj = rem >> 7, e = rem & 127;
      int hh = hj >> 7, j = hj & 127;
      const float* W = which ? Wk : Wq;
      float s = 0.f;
#pragma unroll
      for (int u = 0; u < 16; ++u) s += proj[j * 16 + u] * W[(hh * 16 + u) * 128 + e];
      if (which) Mk[rem] = __float2bfloat16(0.5f * s);
      else       Mq[rem] = __float2bfloat16(0.5f * s);
    }
    if (i < 2048) {
      int which = i >> 10;
      int hj = i & 1023, hh = hj >> 7, j = hj & 127;
      const float* bb = which ? bk : bq;
      float s = 0.f;
#pragma unroll
      for (int u = 0; u < 16; ++u) s += proj[j * 16 + u] * bb[hh * 16 + u];
      if (which) bkf[hj] = 0.5f * s;
      else       bqf[hj] = 0.5f * s;
    }
  }
  if (b < 192) { // prepwb
    int i = b * 256 + t;
    int mat = i >> 14, rem = i & 16383;
    const float* W = (mat == 0) ? Wq : ((mat == 1) ? Wk : Wv);
    Wcat[i] = __float2bfloat16(W[rem]);
    if (i < 384) {
      int m2 = i >> 7;
      const float* bb = (m2 == 0) ? bq : ((m2 == 1) ? bk : bv);
      bcat[i] = bb[i & 127];
    }
  }
}

// ---------------- projection GEMM: Y = x*Wcat^T + bcat ----------------
__global__ __launch_bounds__(256) void k_proj(
    const __hip_bfloat16* __restrict__ xb, const __hip_bfloat16* __restrict__ Wcat,
    const float* __restrict__ bcat, float* __restrict__ Y) {
  __shared__ __align__(16) __bf16 As[4096], Bs[4096];
  const int tm = blockIdx.x << 7, tn = blockIdx.y << 7;
  f32x4 acc[4][4];
  ZERO_ACC(acc);
  gemm_core(xb, Wcat, 128, 128, 128, tm, tn, As, Bs, acc);
  const int t = threadIdx.x, w = t >> 6, lane = t & 63;
  const int m_off = (w >> 1) << 6, n_off = (w & 1) << 6;
#pragma unroll
  for (int ni = 0; ni < 4; ++ni) {
    const int col = tn + n_off + ni * 16 + (lane & 15);
    const float bias = bcat[col];
#pragma unroll
    for (int mi = 0; mi < 4; ++mi)
#pragma unroll
      for (int i = 0; i < 4; ++i) {
        const int row = tm + m_off + mi * 16 + ((lane >> 4) << 2) + i;
        Y[(size_t)row * 384 + col] = acc[mi][ni][i] + bias;
      }
  }
}

// ---------------- vfT build (tiled transpose) ----------------
__global__ void k_vft2(const float* __restrict__ Y, __hip_bfloat16* __restrict__ vfT) {
  const int cb = blockIdx.x, r = blockIdx.y, h = blockIdx.z;
  const int c0 = cb << 7;
  __shared__ float tile[16][132];
  const int t = threadIdx.x;
  const int a = t & 15, cc0 = t >> 4;
#pragma unroll
  for (int i = 0; i < 8; ++i) {
    const int cc = cc0 + (i << 4);
    tile[a][cc] = Y[(size_t)(r * 2048 + c0 + cc) * 384 + 256 + (h << 4) + a];
  }
  __syncthreads();
  const int row = t >> 4, cg = t & 15;
  bf16x8 v;
#pragma unroll
  for (int j = 0; j < 8; ++j) v[j] = (__bf16)tile[row][(cg << 3) + j];
  *(bf16x8*)(vfT + ((size_t)((h << 7) + (r << 4) + row) << 11) + c0 + (cg << 3)) = v;
}

// ---------------- fused q+k dash GEMM ----------------
// q: full feature epilogue (row-max local). k: e = dash-diag (f16) + atomicMax.
__global__ __launch_bounds__(256) void k_dashqk(
    const __hip_bfloat16* __restrict__ xb, const __hip_bfloat16* __restrict__ Mq,
    const __hip_bfloat16* __restrict__ Mk, const float* __restrict__ bqf,
    const float* __restrict__ bkf, const float* __restrict__ Y,
    __hip_bfloat16* __restrict__ qf, _Float16* __restrict__ ek,
    unsigned* __restrict__ kmaxI) {
  __shared__ __align__(16) __bf16 As[4096], Bqs[4096], Bks[4096];
  __shared__ float diagq_s[128], diagk_s[128];
  __shared__ float rmax_s[2][128];
  __shared__ float wmax_s[4];
  const int h = blockIdx.y;
  const int tm = blockIdx.x << 7;
  const int t = threadIdx.x, w = t >> 6, lane = t & 63;
  const int m_off = (w >> 1) << 6, n_off = (w & 1) << 6;
  const int r0 = t >> 2, kk = (t & 3) << 3;
  char* Asb = (char*)As + (w << 10);
  char* Bqb = (char*)Bqs + (w << 10);
  char* Bkb = (char*)Bks + (w << 10);
  const int frow = lane & 15, koff = (lane >> 4) << 3;
  const __hip_bfloat16* Bq_ = Mq + h * 16384;
  const __hip_bfloat16* Bk_ = Mk + h * 16384;
  // diag (persist across loop barriers)
  if (t < 128) {
    const float* yp = Y + (size_t)(tm + t) * 384 + h * 16;
    float s = 0.f;
#pragma unroll
    for (int u = 0; u < 16; ++u) s += yp[u] * yp[u];
    diagq_s[t] = 0.125f * s;
  } else {
    const int tt = t - 128;
    const float* yp = Y + (size_t)(tm + tt) * 384 + 128 + h * 16;
    float s = 0.f;
#pragma unroll
    for (int u = 0; u < 16; ++u) s += yp[u] * yp[u];
    diagk_s[tt] = 0.125f * s;
  }
  f32x4 accq[4][4], acck[4][4];
  ZERO_ACC(accq); ZERO_ACC(acck);
  for (int k0 = 0; k0 < 128; k0 += 32) {
    const __hip_bfloat16* Ag = xb + (size_t)(tm + r0) * 128 + (k0 + kk);
    const __hip_bfloat16* Bg1 = Bq_ + (size_t)r0 * 128 + (k0 + kk);
    const __hip_bfloat16* Bg2 = Bk_ + (size_t)r0 * 128 + (k0 + kk);
    gload16(Ag, Asb);  gload16(Ag + 64 * 128, Asb + 4096);
    gload16(Bg1, Bqb); gload16(Bg1 + 64 * 128, Bqb + 4096);
    gload16(Bg2, Bkb); gload16(Bg2 + 64 * 128, Bkb + 4096);
    __syncthreads();
    bf16x8 af[4], bq1[4], bk1[4];
#pragma unroll
    for (int mi = 0; mi < 4; ++mi)
      af[mi] = *(const bf16x8*)(As + ((m_off + mi * 16 + frow) << 5) + koff);
#pragma unroll
    for (int ni = 0; ni < 4; ++ni) {
      bq1[ni] = *(const bf16x8*)(Bqs + ((n_off + ni * 16 + frow) << 5) + koff);
      bk1[ni] = *(const bf16x8*)(Bks + ((n_off + ni * 16 + frow) << 5) + koff);
    }
#pragma unroll
    for (int mi = 0; mi < 4; ++mi)
#pragma unroll
      for (int ni = 0; ni < 4; ++ni) {
        accq[mi][ni] = __builtin_amdgcn_mfma_f32_16x16x32_bf16(af[mi], bq1[ni], accq[mi][ni], 0, 0, 0);
        acck[mi][ni] = __builtin_amdgcn_mfma_f32_16x16x32_bf16(af[mi], bk1[ni], acck[mi][ni], 0, 0, 0);
      }
    __syncthreads();
  }
  float biaq[4], biak[4];
#pragma unroll
  for (int ni = 0; ni < 4; ++ni) {
    biaq[ni] = bqf[h * 128 + n_off + ni * 16 + frow];
    biak[ni] = bkf[h * 128 + n_off + ni * 16 + frow];
  }
  // q row-max
  float rmx[4][4];
#pragma unroll
  for (int mi = 0; mi < 4; ++mi)
#pragma unroll
    for (int i = 0; i < 4; ++i) {
      float m0 = accq[mi][0][i] + biaq[0];
      m0 = fmaxf(m0, accq[mi][1][i] + biaq[1]);
      m0 = fmaxf(m0, accq[mi][2][i] + biaq[2]);
      m0 = fmaxf(m0, accq[mi][3][i] + biaq[3]);
      rmx[mi][i] = m0;
    }
#pragma unroll
  for (int off = 1; off < 16; off <<= 1)
#pragma unroll
    for (int mi = 0; mi < 4; ++mi)
#pragma unroll
      for (int i = 0; i < 4; ++i)
        rmx[mi][i] = fmaxf(rmx[mi][i], __shfl_xor(rmx[mi][i], off));
  if (frow == 0) {
#pragma unroll
    for (int mi = 0; mi < 4; ++mi)
#pragma unroll
      for (int i = 0; i < 4; ++i)
        rmax_s[w & 1][m_off + mi * 16 + ((lane >> 4) << 2) + i] = rmx[mi][i];
  }
  // k global max (wave)
  float mxk = -1e30f;
#pragma unroll
  for (int ni = 0; ni < 4; ++ni)
#pragma unroll
    for (int mi = 0; mi < 4; ++mi)
#pragma unroll
      for (int i = 0; i < 4; ++i) mxk = fmaxf(mxk, acck[mi][ni][i] + biak[ni]);
#pragma unroll
  for (int off = 1; off < 64; off <<= 1) mxk = fmaxf(mxk, __shfl_xor(mxk, off));
  if (lane == 0) wmax_s[w] = mxk;
  __syncthreads();
  const int r = tm >> 11;
  if (t == 0) {
    float bm = fmaxf(fmaxf(wmax_s[0], wmax_s[1]), fmaxf(wmax_s[2], wmax_s[3]));
    atomicMax(&kmaxI[r * 8 + h], fkey(bm));
  }
  // q feature write + k e write
#pragma unroll
  for (int mi = 0; mi < 4; ++mi) {
#pragma unroll
    for (int i = 0; i < 4; ++i) {
      const int rl = m_off + mi * 16 + ((lane >> 4) << 2) + i;
      const int rg = tm + rl;
      const int c = rg & 2047;
      const float mdq = diagq_s[rl] + fmaxf(rmax_s[0][rl], rmax_s[1][rl]);
      const float dk = diagk_s[rl];
#pragma unroll
      for (int ni = 0; ni < 4; ++ni) {
        const int j = n_off + ni * 16 + frow;
        const float fq = RATIO * (__expf(accq[mi][ni][i] + biaq[ni] - mdq) + EPSV);
        qf[((size_t)((h << 11) + c) << 10) + (r << 7) + j] = __float2bfloat16(fq);
        ek[((size_t)h << 21) + ((size_t)rg << 7) + j] = (_Float16)(acck[mi][ni][i] + biak[ni] - dk);
      }
    }
  }
}

// ---------------- k features: elementwise exp + transpose ----------------
__global__ __launch_bounds__(256) void k_kfeat(
    const _Float16* __restrict__ ek, const unsigned* __restrict__ kmaxI,
    __hip_bfloat16* __restrict__ kf, __hip_bfloat16* __restrict__ kfT) {
  __shared__ __align__(16) __bf16 kT[128 * 136];
  const int h = blockIdx.y, tm = blockIdx.x << 7;
  const int r = tm >> 11, c0 = tm & 2047;
  const float m = funkey(kmaxI[r * 8 + h]);
  const int t = threadIdx.x;
  const int rl = t >> 1, jh = (t & 1) << 6;
  const f16x8* ep = (const f16x8*)(ek + ((size_t)h << 21) + ((size_t)(tm + rl) << 7) + jh);
  const int c = c0 + rl;
  __bf16* kfp = (__bf16*)kf + (((size_t)((h << 11) + c)) << 10) + (r << 7) + jh;
#pragma unroll
  for (int q8 = 0; q8 < 8; ++q8) {
    f16x8 ev = ep[q8];
    bf16x8 fv;
#pragma unroll
    for (int j = 0; j < 8; ++j) {
      const float f = RATIO * (__expf((float)ev[j] - m) + EPSV);
      fv[j] = (__bf16)f;
      kT[(jh + q8 * 8 + j) * 136 + rl] = fv[j];
    }
    *(bf16x8*)(kfp + q8 * 8) = fv;
  }
  __syncthreads();
  const int j2 = t >> 1, half = t & 1;
  __bf16* dst = (__bf16*)kfT + (((size_t)(h << 10) + (r << 7) + j2) << 11) + c0 + (half << 6);
  const __bf16* srcr = kT + j2 * 136 + (half << 6);
#pragma unroll
  for (int q8 = 0; q8 < 8; ++q8)
    *(bf16x8*)(dst + (q8 << 3)) = *(const bf16x8*)(srcr + (q8 << 3));
}

// ---------------- attn GEMM: 256x256, BK=64, 4-phase/K-tile deep pipeline ----
#define SBAR() __builtin_amdgcn_s_barrier()
#define FEN()  do { asm volatile("" ::: "memory"); __builtin_amdgcn_sched_barrier(0); } while (0)
#define PRIO1() __builtin_amdgcn_s_setprio(1)
#define PRIO0() __builtin_amdgcn_s_setprio(0)
#define VMW4() do { asm volatile("s_waitcnt vmcnt(4)" ::: "memory"); } while (0)
#define VMW0() do { asm volatile("s_waitcnt vmcnt(0)" ::: "memory"); } while (0)

#define MFMA16(nlo) do {                                                      \
  _Pragma("unroll") for (int mi_ = 0; mi_ < 8; ++mi_)                         \
  _Pragma("unroll") for (int nj_ = 0; nj_ < 2; ++nj_)                         \
    acc[mi_][(nlo) + nj_] = __builtin_amdgcn_mfma_f32_16x16x32_bf16(          \
        aR[mi_], bR[nj_], acc[mi_][(nlo) + nj_], 0, 0, 0);                    \
} while (0)

__global__ __launch_bounds__(512, 2) void k_attn8(
    const __hip_bfloat16* __restrict__ qf, const __hip_bfloat16* __restrict__ kf,
    float* __restrict__ attn) {
  extern __shared__ __align__(128) char lds[];
  const int lid = blockIdx.x;
  const int swz = ((lid & 7) << 6) + (lid >> 3);
  const int h  = swz >> 6;
  const int tm = ((swz >> 3) & 7) << 8;
  const int tn = (swz & 7) << 8;
  const __hip_bfloat16* Ag = qf + ((size_t)h << 21);
  const __hip_bfloat16* Bg = kf + ((size_t)h << 21);

  const int t = threadIdx.x, wid = t >> 6, lane = t & 63;
  const int f = lane & 15;
  const int wr = wid >> 2, wc = wid & 3;
  const int swzg = (((lane >> 4) ^ ((f >> 1) & 3)) << 4);
  const int aoff = ((wr << 7) + f) * 64 + swzg;
  const int boff = 65536 + ((wc << 6) + f) * 64 + swzg;
  const int srow = t >> 2;
  const int scol = (((t & 3) ^ ((t >> 3) & 3)) << 3);
  const int sdst = wid << 10;

  f32x4 acc[8][4] = {};
  bf16x8 aR[8], bR[2];

  auto stageA = [&](int buf, int kh, int k0) {
    char* d = lds + buf * 32768 + kh * 16384 + sdst;
    const __hip_bfloat16* g = Ag + (size_t)(tm + srow) * 1024 + k0 + (kh << 5) + scol;
    gload16(g, d);
    gload16(g + 128 * 1024, d + 8192);
  };
  auto stageB = [&](int buf, int kh, int k0) {
    char* d = lds + 65536 + buf * 32768 + kh * 16384 + sdst;
    const __hip_bfloat16* g = Bg + (size_t)(tn + srow) * 1024 + k0 + (kh << 5) + scol;
    gload16(g, d);
    gload16(g + 128 * 1024, d + 8192);
  };

  stageA(0, 0, 0); stageB(0, 0, 0); stageA(0, 1, 0); stageB(0, 1, 0);
  VMW4();
  SBAR(); FEN();

  for (int kt = 0; kt < 15; ++kt) {
    const int buf = kt & 1, nbuf = buf ^ 1;
    const int bo = buf * 32768;
    const int nk0 = (kt + 1) << 6;
#pragma unroll
    for (int mi = 0; mi < 8; ++mi) aR[mi] = *(const bf16x8*)(lds + bo + aoff + mi * 1024);
    bR[0] = *(const bf16x8*)(lds + bo + boff);
    bR[1] = *(const bf16x8*)(lds + bo + boff + 1024);
    stageA(nbuf, 0, nk0);
    PRIO1(); MFMA16(0); PRIO0();
    SBAR(); FEN();
    bR[0] = *(const bf16x8*)(lds + bo + boff + 2048);
    bR[1] = *(const bf16x8*)(lds + bo + boff + 3072);
    stageB(nbuf, 0, nk0);
    PRIO1(); MFMA16(2); PRIO0();
    VMW4();
    SBAR(); FEN();
#pragma unroll
    for (int mi = 0; mi < 8; ++mi) aR[mi] = *(const bf16x8*)(lds + bo + 16384 + aoff + mi * 1024);
    bR[0] = *(const bf16x8*)(lds + bo + 16384 + boff);
    bR[1] = *(const bf16x8*)(lds + bo + 16384 + boff + 1024);
    stageA(nbuf, 1, nk0);
    PRIO1(); MFMA16(0); PRIO0();
    SBAR(); FEN();
    bR[0] = *(const bf16x8*)(lds + bo + 16384 + boff + 2048);
    bR[1] = *(const bf16x8*)(lds + bo + 16384 + boff + 3072);
    stageB(nbuf, 1, nk0);
    PRIO1(); MFMA16(2); PRIO0();
    VMW4();
    SBAR(); FEN();
  }
  {
    const int bo = 32768;
#pragma unroll
    for (int mi = 0; mi < 8; ++mi) aR[mi] = *(const bf16x8*)(lds + bo + aoff + mi * 1024);
    bR[0] = *(const bf16x8*)(lds + bo + boff);
    bR[1] = *(const bf16x8*)(lds + bo + boff + 1024);
    PRIO1(); MFMA16(0); PRIO0();
    bR[0] = *(const bf16x8*)(lds + bo + boff + 2048);
    bR[1] = *(const bf16x8*)(lds + bo + boff + 3072);
    PRIO1(); MFMA16(2); PRIO0();
    VMW0();
    SBAR(); FEN();
#pragma unroll
    for (int mi = 0; mi < 8; ++mi) aR[mi] = *(const bf16x8*)(lds + bo + 16384 + aoff + mi * 1024);
    bR[0] = *(const bf16x8*)(lds + bo + 16384 + boff);
    bR[1] = *(const bf16x8*)(lds + bo + 16384 + boff + 1024);
    PRIO1(); MFMA16(0); PRIO0();
    bR[0] = *(const bf16x8*)(lds + bo + 16384 + boff + 2048);
    bR[1] = *(const bf16x8*)(lds + bo + 16384 + boff + 3072);
    PRIO1(); MFMA16(2); PRIO0();
  }

  float* Cc = attn + ((size_t)h << 22);
  const int rbase = tm + (wr << 7) + ((lane >> 4) << 2);
  const int cbase = tn + (wc << 6) + f;
#pragma unroll
  for (int mi = 0; mi < 8; ++mi)
#pragma unroll
    for (int i = 0; i < 4; ++i) {
      float* rp = Cc + ((size_t)(rbase + mi * 16 + i) << 11) + cbase;
#pragma unroll
      for (int ni = 0; ni < 4; ++ni) rp[ni * 16] = acc[mi][ni][i];
    }
}

// ---------------- context GEMM (K-split) + ksum partials ----------------
__global__ __launch_bounds__(256) void k_ctx(
    const __hip_bfloat16* __restrict__ vfT, const __hip_bfloat16* __restrict__ kfT,
    float* __restrict__ ctxp, float* __restrict__ ksump) {
  __shared__ __align__(16) __bf16 As[4096], Bs[4096];
  const int z = blockIdx.z, h = z >> 2, kc = z & 3;
  const int tn = blockIdx.y << 7;
  const int t = threadIdx.x, w = t >> 6, lane = t & 63;
  const int m_off = (w >> 1) << 6, n_off = (w & 1) << 6;
  const int r0 = t >> 2, kk = (t & 3) << 3;
  char* Asb = (char*)As + (w << 10);
  char* Bsb = (char*)Bs + (w << 10);
  const int frow = lane & 15, koff = (lane >> 4) << 3;
  const __hip_bfloat16* A = vfT + ((size_t)h << 18) + (kc << 9);
  const __hip_bfloat16* B = kfT + ((size_t)h << 21) + (kc << 9);
  f32x4 acc[4][4];
  ZERO_ACC(acc);
  float bsum[4] = {0.f, 0.f, 0.f, 0.f};
  for (int k0 = 0; k0 < 512; k0 += 32) {
    const __hip_bfloat16* Ag = A + (size_t)r0 * 2048 + (k0 + kk);
    const __hip_bfloat16* Bg = B + (size_t)(tn + r0) * 2048 + (k0 + kk);
    gload16(Ag, Asb);
    gload16(Ag + (size_t)64 * 2048, Asb + 4096);
    gload16(Bg, Bsb);
    gload16(Bg + (size_t)64 * 2048, Bsb + 4096);
    __syncthreads();
    bf16x8 af[4], bfr[4];
#pragma unroll
    for (int mi = 0; mi < 4; ++mi)
      af[mi] = *(const bf16x8*)(As + ((m_off + mi * 16 + frow) << 5) + koff);
#pragma unroll
    for (int ni = 0; ni < 4; ++ni) {
      bfr[ni] = *(const bf16x8*)(Bs + ((n_off + ni * 16 + frow) << 5) + koff);
#pragma unroll
      for (int j = 0; j < 8; ++j) bsum[ni] += (float)bfr[ni][j];
    }
#pragma unroll
    for (int mi = 0; mi < 4; ++mi)
#pragma unroll
      for (int ni = 0; ni < 4; ++ni)
        acc[mi][ni] = __builtin_amdgcn_mfma_f32_16x16x32_bf16(af[mi], bfr[ni], acc[mi][ni], 0, 0, 0);
    __syncthreads();
  }
  // ksum partials: reduce across koff groups, write once per d
#pragma unroll
  for (int ni = 0; ni < 4; ++ni) {
    bsum[ni] += __shfl_xor(bsum[ni], 16);
    bsum[ni] += __shfl_xor(bsum[ni], 32);
  }
  if (w < 2 && (lane >> 4) == 0) {
#pragma unroll
    for (int ni = 0; ni < 4; ++ni)
      ksump[(((kc << 3) + h) << 10) + tn + n_off + ni * 16 + frow] = bsum[ni];
  }
  float* Cp = ctxp + ((size_t)((kc << 3) + h) << 17);
#pragma unroll
  for (int mi = 0; mi < 4; ++mi)
#pragma unroll
    for (int i = 0; i < 4; ++i) {
      const int row = m_off + mi * 16 + ((lane >> 4) << 2) + i;
#pragma unroll
      for (int ni = 0; ni < 4; ++ni) {
        const int col = tn + n_off + ni * 16 + frow;
        Cp[((size_t)row << 10) + col] = acc[mi][ni][i];
      }
    }
}

__global__ void k_ctxred(const float* __restrict__ ctxp, __hip_bfloat16* __restrict__ ctxT) {
  const int i = blockIdx.x * 256 + threadIdx.x;
  const float s = ctxp[i] + ctxp[i + 1048576] + ctxp[i + 2097152] + ctxp[i + 3145728];
  ctxT[i] = __float2bfloat16(s);
}

// ---------------- out GEMM + fused dinv + scatter ----------------
__global__ __launch_bounds__(256) void k_out(
    const __hip_bfloat16* __restrict__ qf, const __hip_bfloat16* __restrict__ ctxT,
    const float* __restrict__ ksump, float* __restrict__ outp) {
  __shared__ __align__(16) __bf16 As[4096], Bs[4096];
  __shared__ float ksum_s[1024];
  __shared__ float dsum_s[2][128];
  const int h = blockIdx.z;
  const int tm = blockIdx.x << 7;
  const int t = threadIdx.x, w = t >> 6, lane = t & 63;
  const int m_off = (w >> 1) << 6, n_off = (w & 1) << 6;
  const int r0 = t >> 2, kk = (t & 3) << 3;
  char* Asb = (char*)As + (w << 10);
  char* Bsb = (char*)Bs + (w << 10);
  const int frow = lane & 15, koff = (lane >> 4) << 3;
  const __hip_bfloat16* A = qf + ((size_t)h << 21);
  const __hip_bfloat16* B = ctxT + ((size_t)h << 17);
#pragma unroll
  for (int it = 0; it < 4; ++it) {
    const int d = t + it * 256;
    ksum_s[d] = ksump[(h << 10) + d] + ksump[((8 + h) << 10) + d] +
                ksump[((16 + h) << 10) + d] + ksump[((24 + h) << 10) + d];
  }
  f32x4 acc[4][4];
  ZERO_ACC(acc);
  const int drow = t & 127, dh = t >> 7;
  const int dsw = (drow >> 1) & 3;
  float dot = 0.f;
  for (int k0 = 0; k0 < 1024; k0 += 32) {
    const __hip_bfloat16* Ag = A + (size_t)(tm + r0) * 1024 + (k0 + kk);
    const __hip_bfloat16* Bg = B + (size_t)r0 * 1024 + (k0 + kk);
    gload16(Ag, Asb);
    gload16(Ag + (size_t)64 * 1024, Asb + 4096);
    gload16(Bg, Bsb);
    gload16(Bg + (size_t)64 * 1024, Bsb + 4096);
    __syncthreads();
    bf16x8 af[4], bfr[4];
#pragma unroll
    for (int mi = 0; mi < 4; ++mi)
      af[mi] = *(const bf16x8*)(As + ((m_off + mi * 16 + frow) << 5) + koff);
#pragma unroll
    for (int ni = 0; ni < 4; ++ni)
      bfr[ni] = *(const bf16x8*)(Bs + ((n_off + ni * 16 + frow) << 5) + koff);
    // fused dinv partial: row(drow) dot ksum over this k-window
#pragma unroll
    for (int u = 0; u < 2; ++u) {
      const int g = ((dh << 1) + u) ^ dsw;
      bf16x8 av = *(const bf16x8*)((char*)As + drow * 64 + g * 16);
      const float* kp = &ksum_s[k0 + (g << 3)];
#pragma unroll
      for (int j = 0; j < 8; ++j) dot += (float)av[j] * kp[j];
    }
#pragma unroll
    for (int mi = 0; mi < 4; ++mi)
#pragma unroll
      for (int ni = 0; ni < 4; ++ni)
        acc[mi][ni] = __builtin_amdgcn_mfma_f32_16x16x32_bf16(af[mi], bfr[ni], acc[mi][ni], 0, 0, 0);
    __syncthreads();
  }
  dsum_s[dh][drow] = dot;
  __syncthreads();
#pragma unroll
  for (int mi = 0; mi < 4; ++mi)
#pragma unroll
    for (int i = 0; i < 4; ++i) {
      const int rl = m_off + mi * 16 + ((lane >> 4) << 2) + i;
      const int row = tm + rl;
      const float dv = 1.0f / (dsum_s[0][rl] + dsum_s[1][rl]);
#pragma unroll
      for (int ni = 0; ni < 4; ++ni) {
        const int col = n_off + ni * 16 + frow;
        const int rb = col >> 4, tt = col & 15;
        outp[(((size_t)(rb << 11) + row) << 7) + (h << 4) + tt] = acc[mi][ni][i] * dv;
      }
    }
}

// ---------------- launch ----------------
extern "C" void kernel_launch(void* const* d_in, const int* in_sizes, int n_in,
                              void* d_out, int out_size, void* d_ws, size_t ws_size,
                              hipStream_t stream) {
  const float* x    = (const float*)d_in[0];
  const float* Wq   = (const float*)d_in[1];
  const float* bq   = (const float*)d_in[2];
  const float* Wk   = (const float*)d_in[3];
  const float* bk   = (const float*)d_in[4];
  const float* Wv   = (const float*)d_in[5];
  const float* bv   = (const float*)d_in[6];
  const float* proj = (const float*)d_in[7];
  if (ws_size < WS_NEED) return;

  char* ws = (char*)d_ws;
  __hip_bfloat16* xb   = (__hip_bfloat16*)(ws + OFF_XB);
  __hip_bfloat16* Wcat = (__hip_bfloat16*)(ws + OFF_WCAT);
  __hip_bfloat16* Mq   = (__hip_bfloat16*)(ws + OFF_MQ);
  __hip_bfloat16* Mk   = (__hip_bfloat16*)(ws + OFF_MK);
  float* bcat = (float*)(ws + OFF_BCAT);
  float* bqf  = (float*)(ws + OFF_BQF);
  float* bkf  = (float*)(ws + OFF_BKF);
  float* Y    = (float*)(ws + OFF_Y);
  __hip_bfloat16* qf  = (__hip_bfloat16*)(ws + OFF_QF);
  __hip_bfloat16* kf  = (__hip_bfloat16*)(ws + OFF_KF);
  __hip_bfloat16* kfT = (__hip_bfloat16*)(ws + OFF_KFT);
  __hip_bfloat16* vfT = (__hip_bfloat16*)(ws + OFF_VFT);
  unsigned* kmaxI = (unsigned*)(ws + OFF_KMAXI);
  float* ksump = (float*)(ws + OFF_KSUMP);
  _Float16* ek = (_Float16*)(ws + OFF_EK);
  float* ctxp  = (float*)(ws + OFF_CTXP);
  __hip_bfloat16* ctxT = (__hip_bfloat16*)(ws + OFF_CTXT);

  float* outp = (float*)d_out;
  float* attn = (float*)d_out + 2097152;

  static int attr_done = 0;
  if (!attr_done) {
    (void)hipFuncSetAttribute((const void*)k_attn8,
                              hipFuncAttributeMaxDynamicSharedMemorySize, 131072);
    attr_done = 1;
  }

  k_prep<<<dim3(2048), dim3(256), 0, stream>>>(x, Wq, bq, Wk, bk, Wv, bv, proj,
                                               xb, Wcat, bcat, Mq, Mk, bqf, bkf, kmaxI);
  k_proj<<<dim3(128, 3), dim3(256), 0, stream>>>(xb, Wcat, bcat, Y);
  k_vft2<<<dim3(16, 8, 8), dim3(256), 0, stream>>>(Y, vfT);
  k_dashqk<<<dim3(128, 8), dim3(256), 0, stream>>>(xb, Mq, Mk, bqf, bkf, Y, qf, ek, kmaxI);
  k_kfeat<<<dim3(128, 8), dim3(256), 0, stream>>>(ek, kmaxI, kf, kfT);
  k_attn8<<<dim3(512), dim3(512), 131072, stream>>>(qf, kf, attn);
  k_ctx<<<dim3(1, 8, 32), dim3(256), 0, stream>>>(vfT, kfT, ctxp, ksump);
  k_ctxred<<<dim3(4096), dim3(256), 0, stream>>>(ctxp, ctxT);
  k_out<<<dim3(16, 1, 8), dim3(256), 0, stream>>>(qf, ctxT, ksump, outp);
}

// Round 6
// 222.972 us; speedup vs baseline: 1.0251x; 1.0251x over previous
//
#include <hip/hip_runtime.h>
#include <hip/hip_bf16.h>
#include <stdint.h>

typedef __bf16 bf16x8 __attribute__((ext_vector_type(8)));
typedef _Float16 f16x8 __attribute__((ext_vector_type(8)));
typedef float  f32x4  __attribute__((ext_vector_type(4)));

#define RATIO 0.08838834764831845f
#define EPSV  1e-4f

#define GLOBAL_AS __attribute__((address_space(1)))
#define LDS_AS    __attribute__((address_space(3)))

static __device__ __forceinline__ void gload16(const void* g, void* l) {
  __builtin_amdgcn_global_load_lds((GLOBAL_AS const void*)g, (LDS_AS void*)l, 16, 0, 0);
}

// monotonic float<->uint key for exact atomicMax
static __device__ __forceinline__ unsigned fkey(float f) {
  unsigned b = __float_as_uint(f);
  return (b & 0x80000000u) ? ~b : (b | 0x80000000u);
}
static __device__ __forceinline__ float funkey(unsigned k) {
  unsigned b = (k & 0x80000000u) ? (k & 0x7FFFFFFFu) : ~k;
  return __uint_as_float(b);
}

// ---------------- workspace layout (bytes) ----------------
static constexpr size_t OFF_XB    = 0;                        // 16384*128*2
static constexpr size_t OFF_WCAT  = OFF_XB    + 4194304;
static constexpr size_t OFF_MQ    = OFF_WCAT  + 98304;
static constexpr size_t OFF_MK    = OFF_MQ    + 262144;
static constexpr size_t OFF_BCAT  = OFF_MK    + 262144;
static constexpr size_t OFF_BQF   = OFF_BCAT  + 2048;
static constexpr size_t OFF_BKF   = OFF_BQF   + 4096;
static constexpr size_t OFF_Y     = OFF_BKF   + 4096;         // 16384*384*4
static constexpr size_t OFF_QF    = OFF_Y     + 25165824;     // 8*2048*1024*2
static constexpr size_t OFF_KF    = OFF_QF    + 33554432;
static constexpr size_t OFF_KFT   = OFF_KF    + 33554432;
static constexpr size_t OFF_VFT   = OFF_KFT   + 33554432;     // 8*128*2048*2
static constexpr size_t OFF_KMAXI = OFF_VFT   + 4194304;      // 64*4 (pad 1024)
static constexpr size_t OFF_KSUMP = OFF_KMAXI + 1024;         // 4*8*1024*4
static constexpr size_t OFF_EK    = OFF_KSUMP + 131072;       // 8*16384*128*2
static constexpr size_t OFF_CTXP  = OFF_EK    + 33554432;     // 4*8*128*1024*4
static constexpr size_t OFF_CTXT  = OFF_CTXP  + 16777216;     // 8*128*1024*2
static constexpr size_t WS_NEED   = OFF_CTXT  + 2097152;

// ---------------- shared NT-GEMM core: C(128x128) = A(tm:,*) * B(tn:,*)^T ----
static __device__ __forceinline__ void gemm_core(
    const __hip_bfloat16* __restrict__ A, const __hip_bfloat16* __restrict__ B,
    int lda, int ldb, int K, int tm, int tn,
    __bf16* As, __bf16* Bs, f32x4 acc[4][4]) {
  const int t    = threadIdx.x;
  const int w    = t >> 6;
  const int lane = t & 63;
  const int m_off = (w >> 1) << 6;
  const int n_off = (w & 1) << 6;
  const int r0 = t >> 2;
  const int kk = (t & 3) << 3;
  char* Asb = (char*)As + (w << 10);
  char* Bsb = (char*)Bs + (w << 10);
  const int frow = lane & 15;
  const int koff = (lane >> 4) << 3;
  for (int k0 = 0; k0 < K; k0 += 32) {
    const __hip_bfloat16* Ag = A + (size_t)(tm + r0) * lda + (k0 + kk);
    const __hip_bfloat16* Bg = B + (size_t)(tn + r0) * ldb + (k0 + kk);
    gload16(Ag, Asb);
    gload16(Ag + (size_t)64 * lda, Asb + 4096);
    gload16(Bg, Bsb);
    gload16(Bg + (size_t)64 * ldb, Bsb + 4096);
    __syncthreads();
    bf16x8 af[4], bfr[4];
#pragma unroll
    for (int mi = 0; mi < 4; ++mi)
      af[mi] = *(const bf16x8*)(As + ((m_off + mi * 16 + frow) << 5) + koff);
#pragma unroll
    for (int ni = 0; ni < 4; ++ni)
      bfr[ni] = *(const bf16x8*)(Bs + ((n_off + ni * 16 + frow) << 5) + koff);
#pragma unroll
    for (int mi = 0; mi < 4; ++mi)
#pragma unroll
      for (int ni = 0; ni < 4; ++ni)
        acc[mi][ni] = __builtin_amdgcn_mfma_f32_16x16x32_bf16(af[mi], bfr[ni], acc[mi][ni], 0, 0, 0);
    __syncthreads();
  }
}

#define ZERO_ACC(acc) do {                                   \
  _Pragma("unroll") for (int a_ = 0; a_ < 4; ++a_)           \
  _Pragma("unroll") for (int b_ = 0; b_ < 4; ++b_)           \
    acc[a_][b_] = (f32x4){0.f, 0.f, 0.f, 0.f};               \
} while (0)

// ---------------- fused prep kernel ----------------
__global__ void k_prep(const float* __restrict__ x,
                       const float* __restrict__ Wq, const float* __restrict__ bq,
                       const float* __restrict__ Wk, const float* __restrict__ bk,
                       const float* __restrict__ Wv, const float* __restrict__ bv,
                       const float* __restrict__ proj,
                       __hip_bfloat16* __restrict__ xb,
                       __hip_bfloat16* __restrict__ Wcat, float* __restrict__ bcat,
                       __hip_bfloat16* __restrict__ Mq, __hip_bfloat16* __restrict__ Mk,
                       float* __restrict__ bqf, float* __restrict__ bkf,
                       unsigned* __restrict__ kmaxI) {
  const int b = blockIdx.x, t = threadIdx.x;
  { // convx: all 2048 blocks
    int i = (b * 256 + t) * 4;
    f32x4 v = *(const f32x4*)(x + i);
#pragma unroll
    for (int j = 0; j < 4; ++j) xb[i + j] = __float2bfloat16(v[j]);
  }
  if (b == 0 && t < 64) kmaxI[t] = 0u;
  if (b < 1024) { // prepM
    int i = b * 256 + t;
    {
      int which = i >> 17;
      int rem = i & 131071;
      int hj = rem >> 7, e = rem & 127;
      int hh = hj >> 7, j = hj & 127;
      const float* W = which ? Wk : Wq;
      float s = 0.f;
#pragma unroll
      for (int u = 0; u < 16; ++u) s += proj[j * 16 + u] * W[(hh * 16 + u) * 128 + e];
      if (which) Mk[rem] = __float2bfloat16(0.5f * s);
      else       Mq[rem] = __float2bfloat16(0.5f * s);
    }
    if (i < 2048) {
      int which = i >> 10;
      int hj = i & 1023, hh = hj >> 7, j = hj & 127;
      const float* bb = which ? bk : bq;
      float s = 0.f;
#pragma unroll
      for (int u = 0; u < 16; ++u) s += proj[j * 16 + u] * bb[hh * 16 + u];
      if (which) bkf[hj] = 0.5f * s;
      else       bqf[hj] = 0.5f * s;
    }
  }
  if (b < 192) { // prepwb
    int i = b * 256 + t;
    int mat = i >> 14, rem = i & 16383;
    const float* W = (mat == 0) ? Wq : ((mat == 1) ? Wk : Wv);
    Wcat[i] = __float2bfloat16(W[rem]);
    if (i < 384) {
      int m2 = i >> 7;
      const float* bb = (m2 == 0) ? bq : ((m2 == 1) ? bk : bv);
      bcat[i] = bb[i & 127];
    }
  }
}

// ---------------- projection GEMM: Y = x*Wcat^T + bcat ----------------
__global__ __launch_bounds__(256) void k_proj(
    const __hip_bfloat16* __restrict__ xb, const __hip_bfloat16* __restrict__ Wcat,
    const float* __restrict__ bcat, float* __restrict__ Y) {
  __shared__ __align__(16) __bf16 As[4096], Bs[4096];
  const int tm = blockIdx.x << 7, tn = blockIdx.y << 7;
  f32x4 acc[4][4];
  ZERO_ACC(acc);
  gemm_core(xb, Wcat, 128, 128, 128, tm, tn, As, Bs, acc);
  const int t = threadIdx.x, w = t >> 6, lane = t & 63;
  const int m_off = (w >> 1) << 6, n_off = (w & 1) << 6;
#pragma unroll
  for (int ni = 0; ni < 4; ++ni) {
    const int col = tn + n_off + ni * 16 + (lane & 15);
    const float bias = bcat[col];
#pragma unroll
    for (int mi = 0; mi < 4; ++mi)
#pragma unroll
      for (int i = 0; i < 4; ++i) {
        const int row = tm + m_off + mi * 16 + ((lane >> 4) << 2) + i;
        Y[(size_t)row * 384 + col] = acc[mi][ni][i] + bias;
      }
  }
}

// ---------------- vfT build (tiled transpose) ----------------
__global__ void k_vft2(const float* __restrict__ Y, __hip_bfloat16* __restrict__ vfT) {
  const int cb = blockIdx.x, r = blockIdx.y, h = blockIdx.z;
  const int c0 = cb << 7;
  __shared__ float tile[16][132];
  const int t = threadIdx.x;
  const int a = t & 15, cc0 = t >> 4;
#pragma unroll
  for (int i = 0; i < 8; ++i) {
    const int cc = cc0 + (i << 4);
    tile[a][cc] = Y[(size_t)(r * 2048 + c0 + cc) * 384 + 256 + (h << 4) + a];
  }
  __syncthreads();
  const int row = t >> 4, cg = t & 15;
  bf16x8 v;
#pragma unroll
  for (int j = 0; j < 8; ++j) v[j] = (__bf16)tile[row][(cg << 3) + j];
  *(bf16x8*)(vfT + ((size_t)((h << 7) + (r << 4) + row) << 11) + c0 + (cg << 3)) = v;
}

// ---------------- q features (proven round-4 version) ----------------
__global__ __launch_bounds__(256) void k_dashq(
    const __hip_bfloat16* __restrict__ xb, const __hip_bfloat16* __restrict__ Mq,
    const float* __restrict__ bqf, const float* __restrict__ Y,
    __hip_bfloat16* __restrict__ qf) {
  __shared__ __align__(16) __bf16 As[4096], Bs[4096];
  __shared__ float diag_s[128];
  __shared__ float rmax_s[2][128];
  const int h = blockIdx.y;
  const int tm = blockIdx.x << 7;
  f32x4 acc[4][4];
  ZERO_ACC(acc);
  gemm_core(xb, Mq + h * 16384, 128, 128, 128, tm, 0, As, Bs, acc);
  const int t = threadIdx.x, w = t >> 6, lane = t & 63;
  const int m_off = (w >> 1) << 6, n_off = (w & 1) << 6;
  if (t < 128) {
    const float* yp = Y + (size_t)(tm + t) * 384 + h * 16;
    float s = 0.f;
#pragma unroll
    for (int u = 0; u < 16; ++u) s += yp[u] * yp[u];
    diag_s[t] = 0.125f * s;
  }
  float bia[4];
#pragma unroll
  for (int ni = 0; ni < 4; ++ni) bia[ni] = bqf[h * 128 + n_off + ni * 16 + (lane & 15)];
  float rmx[4][4];
#pragma unroll
  for (int mi = 0; mi < 4; ++mi)
#pragma unroll
    for (int i = 0; i < 4; ++i) {
      float m0 = acc[mi][0][i] + bia[0];
      m0 = fmaxf(m0, acc[mi][1][i] + bia[1]);
      m0 = fmaxf(m0, acc[mi][2][i] + bia[2]);
      m0 = fmaxf(m0, acc[mi][3][i] + bia[3]);
      rmx[mi][i] = m0;
    }
#pragma unroll
  for (int off = 1; off < 16; off <<= 1)
#pragma unroll
    for (int mi = 0; mi < 4; ++mi)
#pragma unroll
      for (int i = 0; i < 4; ++i)
        rmx[mi][i] = fmaxf(rmx[mi][i], __shfl_xor(rmx[mi][i], off));
  if ((lane & 15) == 0) {
#pragma unroll
    for (int mi = 0; mi < 4; ++mi)
#pragma unroll
      for (int i = 0; i < 4; ++i)
        rmax_s[w & 1][m_off + mi * 16 + ((lane >> 4) << 2) + i] = rmx[mi][i];
  }
  __syncthreads();
#pragma unroll
  for (int mi = 0; mi < 4; ++mi) {
#pragma unroll
    for (int i = 0; i < 4; ++i) {
      const int rl = m_off + mi * 16 + ((lane >> 4) << 2) + i;
      const int rg = tm + rl;
      const int c = rg & 2047, r = rg >> 11;
      const float md = diag_s[rl] + fmaxf(rmax_s[0][rl], rmax_s[1][rl]);
#pragma unroll
      for (int ni = 0; ni < 4; ++ni) {
        const int j = n_off + ni * 16 + (lane & 15);
        const float f = RATIO * (__expf(acc[mi][ni][i] + bia[ni] - md) + EPSV);
        qf[((size_t)((h << 11) + c) << 10) + (r << 7) + j] = __float2bfloat16(f);
      }
    }
  }
}

// ---------------- k dash: single GEMM -> e (f16) + exact atomic max ----------
__global__ __launch_bounds__(256) void k_dashk_e(
    const __hip_bfloat16* __restrict__ xb, const __hip_bfloat16* __restrict__ Mk,
    const float* __restrict__ bkf, const float* __restrict__ Y,
    _Float16* __restrict__ ek, unsigned* __restrict__ kmaxI) {
  __shared__ __align__(16) __bf16 As[4096], Bs[4096];
  __shared__ float diag_s[128];
  __shared__ float wmax_s[4];
  const int h = blockIdx.y;
  const int tm = blockIdx.x << 7;
  f32x4 acc[4][4];
  ZERO_ACC(acc);
  gemm_core(xb, Mk + h * 16384, 128, 128, 128, tm, 0, As, Bs, acc);
  const int t = threadIdx.x, w = t >> 6, lane = t & 63;
  const int m_off = (w >> 1) << 6, n_off = (w & 1) << 6;
  const int frow = lane & 15;
  if (t < 128) {
    const float* yp = Y + (size_t)(tm + t) * 384 + 128 + h * 16;
    float s = 0.f;
#pragma unroll
    for (int u = 0; u < 16; ++u) s += yp[u] * yp[u];
    diag_s[t] = 0.125f * s;
  }
  float bia[4];
#pragma unroll
  for (int ni = 0; ni < 4; ++ni) bia[ni] = bkf[h * 128 + n_off + ni * 16 + frow];
  float mxk = -1e30f;
#pragma unroll
  for (int ni = 0; ni < 4; ++ni)
#pragma unroll
    for (int mi = 0; mi < 4; ++mi)
#pragma unroll
      for (int i = 0; i < 4; ++i) mxk = fmaxf(mxk, acc[mi][ni][i] + bia[ni]);
#pragma unroll
  for (int off = 1; off < 64; off <<= 1) mxk = fmaxf(mxk, __shfl_xor(mxk, off));
  if (lane == 0) wmax_s[w] = mxk;
  __syncthreads();
  const int r = tm >> 11;
  if (t == 0) {
    float bm = fmaxf(fmaxf(wmax_s[0], wmax_s[1]), fmaxf(wmax_s[2], wmax_s[3]));
    atomicMax(&kmaxI[r * 8 + h], fkey(bm));
  }
#pragma unroll
  for (int mi = 0; mi < 4; ++mi) {
#pragma unroll
    for (int i = 0; i < 4; ++i) {
      const int rl = m_off + mi * 16 + ((lane >> 4) << 2) + i;
      const int rg = tm + rl;
      const float dk = diag_s[rl];
#pragma unroll
      for (int ni = 0; ni < 4; ++ni) {
        const int j = n_off + ni * 16 + frow;
        ek[((size_t)h << 21) + ((size_t)rg << 7) + j] = (_Float16)(acc[mi][ni][i] + bia[ni] - dk);
      }
    }
  }
}

// ---------------- k features: elementwise exp + transpose ----------------
__global__ __launch_bounds__(256) void k_kfeat(
    const _Float16* __restrict__ ek, const unsigned* __restrict__ kmaxI,
    __hip_bfloat16* __restrict__ kf, __hip_bfloat16* __restrict__ kfT) {
  __shared__ __align__(16) __bf16 kT[128 * 136];
  const int h = blockIdx.y, tm = blockIdx.x << 7;
  const int r = tm >> 11, c0 = tm & 2047;
  const float m = funkey(kmaxI[r * 8 + h]);
  const int t = threadIdx.x;
  const int rl = t >> 1, jh = (t & 1) << 6;
  const f16x8* ep = (const f16x8*)(ek + ((size_t)h << 21) + ((size_t)(tm + rl) << 7) + jh);
  const int c = c0 + rl;
  __bf16* kfp = (__bf16*)kf + (((size_t)((h << 11) + c)) << 10) + (r << 7) + jh;
#pragma unroll
  for (int q8 = 0; q8 < 8; ++q8) {
    f16x8 ev = ep[q8];
    bf16x8 fv;
#pragma unroll
    for (int j = 0; j < 8; ++j) {
      const float f = RATIO * (__expf((float)ev[j] - m) + EPSV);
      fv[j] = (__bf16)f;
      kT[(jh + q8 * 8 + j) * 136 + rl] = fv[j];
    }
    *(bf16x8*)(kfp + q8 * 8) = fv;
  }
  __syncthreads();
  const int j2 = t >> 1, half = t & 1;
  __bf16* dst = (__bf16*)kfT + (((size_t)(h << 10) + (r << 7) + j2) << 11) + c0 + (half << 6);
  const __bf16* srcr = kT + j2 * 136 + (half << 6);
#pragma unroll
  for (int q8 = 0; q8 < 8; ++q8)
    *(bf16x8*)(dst + (q8 << 3)) = *(const bf16x8*)(srcr + (q8 << 3));
}

// ---------------- attn GEMM: 256x256, BK=64, 4-phase/K-tile deep pipeline ----
#define SBAR() __builtin_amdgcn_s_barrier()
#define FEN()  do { asm volatile("" ::: "memory"); __builtin_amdgcn_sched_barrier(0); } while (0)
#define PRIO1() __builtin_amdgcn_s_setprio(1)
#define PRIO0() __builtin_amdgcn_s_setprio(0)
#define VMW4() do { asm volatile("s_waitcnt vmcnt(4)" ::: "memory"); } while (0)
#define VMW0() do { asm volatile("s_waitcnt vmcnt(0)" ::: "memory"); } while (0)

#define MFMA16(nlo) do {                                                      \
  _Pragma("unroll") for (int mi_ = 0; mi_ < 8; ++mi_)                         \
  _Pragma("unroll") for (int nj_ = 0; nj_ < 2; ++nj_)                         \
    acc[mi_][(nlo) + nj_] = __builtin_amdgcn_mfma_f32_16x16x32_bf16(          \
        aR[mi_], bR[nj_], acc[mi_][(nlo) + nj_], 0, 0, 0);                    \
} while (0)

__global__ __launch_bounds__(512, 2) void k_attn8(
    const __hip_bfloat16* __restrict__ qf, const __hip_bfloat16* __restrict__ kf,
    float* __restrict__ attn) {
  extern __shared__ __align__(128) char lds[];
  const int lid = blockIdx.x;
  const int swz = ((lid & 7) << 6) + (lid >> 3);
  const int h  = swz >> 6;
  const int tm = ((swz >> 3) & 7) << 8;
  const int tn = (swz & 7) << 8;
  const __hip_bfloat16* Ag = qf + ((size_t)h << 21);
  const __hip_bfloat16* Bg = kf + ((size_t)h << 21);

  const int t = threadIdx.x, wid = t >> 6, lane = t & 63;
  const int f = lane & 15;
  const int wr = wid >> 2, wc = wid & 3;
  const int swzg = (((lane >> 4) ^ ((f >> 1) & 3)) << 4);
  const int aoff = ((wr << 7) + f) * 64 + swzg;
  const int boff = 65536 + ((wc << 6) + f) * 64 + swzg;
  const int srow = t >> 2;
  const int scol = (((t & 3) ^ ((t >> 3) & 3)) << 3);
  const int sdst = wid << 10;

  f32x4 acc[8][4] = {};
  bf16x8 aR[8], bR[2];

  auto stageA = [&](int buf, int kh, int k0) {
    char* d = lds + buf * 32768 + kh * 16384 + sdst;
    const __hip_bfloat16* g = Ag + (size_t)(tm + srow) * 1024 + k0 + (kh << 5) + scol;
    gload16(g, d);
    gload16(g + 128 * 1024, d + 8192);
  };
  auto stageB = [&](int buf, int kh, int k0) {
    char* d = lds + 65536 + buf * 32768 + kh * 16384 + sdst;
    const __hip_bfloat16* g = Bg + (size_t)(tn + srow) * 1024 + k0 + (kh << 5) + scol;
    gload16(g, d);
    gload16(g + 128 * 1024, d + 8192);
  };

  stageA(0, 0, 0); stageB(0, 0, 0); stageA(0, 1, 0); stageB(0, 1, 0);
  VMW4();
  SBAR(); FEN();

  for (int kt = 0; kt < 15; ++kt) {
    const int buf = kt & 1, nbuf = buf ^ 1;
    const int bo = buf * 32768;
    const int nk0 = (kt + 1) << 6;
#pragma unroll
    for (int mi = 0; mi < 8; ++mi) aR[mi] = *(const bf16x8*)(lds + bo + aoff + mi * 1024);
    bR[0] = *(const bf16x8*)(lds + bo + boff);
    bR[1] = *(const bf16x8*)(lds + bo + boff + 1024);
    stageA(nbuf, 0, nk0);
    PRIO1(); MFMA16(0); PRIO0();
    SBAR(); FEN();
    bR[0] = *(const bf16x8*)(lds + bo + boff + 2048);
    bR[1] = *(const bf16x8*)(lds + bo + boff + 3072);
    stageB(nbuf, 0, nk0);
    PRIO1(); MFMA16(2); PRIO0();
    VMW4();
    SBAR(); FEN();
#pragma unroll
    for (int mi = 0; mi < 8; ++mi) aR[mi] = *(const bf16x8*)(lds + bo + 16384 + aoff + mi * 1024);
    bR[0] = *(const bf16x8*)(lds + bo + 16384 + boff);
    bR[1] = *(const bf16x8*)(lds + bo + 16384 + boff + 1024);
    stageA(nbuf, 1, nk0);
    PRIO1(); MFMA16(0); PRIO0();
    SBAR(); FEN();
    bR[0] = *(const bf16x8*)(lds + bo + 16384 + boff + 2048);
    bR[1] = *(const bf16x8*)(lds + bo + 16384 + boff + 3072);
    stageB(nbuf, 1, nk0);
    PRIO1(); MFMA16(2); PRIO0();
    VMW4();
    SBAR(); FEN();
  }
  {
    const int bo = 32768;
#pragma unroll
    for (int mi = 0; mi < 8; ++mi) aR[mi] = *(const bf16x8*)(lds + bo + aoff + mi * 1024);
    bR[0] = *(const bf16x8*)(lds + bo + boff);
    bR[1] = *(const bf16x8*)(lds + bo + boff + 1024);
    PRIO1(); MFMA16(0); PRIO0();
    bR[0] = *(const bf16x8*)(lds + bo + boff + 2048);
    bR[1] = *(const bf16x8*)(lds + bo + boff + 3072);
    PRIO1(); MFMA16(2); PRIO0();
    VMW0();
    SBAR(); FEN();
#pragma unroll
    for (int mi = 0; mi < 8; ++mi) aR[mi] = *(const bf16x8*)(lds + bo + 16384 + aoff + mi * 1024);
    bR[0] = *(const bf16x8*)(lds + bo + 16384 + boff);
    bR[1] = *(const bf16x8*)(lds + bo + 16384 + boff + 1024);
    PRIO1(); MFMA16(0); PRIO0();
    bR[0] = *(const bf16x8*)(lds + bo + 16384 + boff + 2048);
    bR[1] = *(const bf16x8*)(lds + bo + 16384 + boff + 3072);
    PRIO1(); MFMA16(2); PRIO0();
  }

  float* Cc = attn + ((size_t)h << 22);
  const int rbase = tm + (wr << 7) + ((lane >> 4) << 2);
  const int cbase = tn + (wc << 6) + f;
#pragma unroll
  for (int mi = 0; mi < 8; ++mi)
#pragma unroll
    for (int i = 0; i < 4; ++i) {
      float* rp = Cc + ((size_t)(rbase + mi * 16 + i) << 11) + cbase;
#pragma unroll
      for (int ni = 0; ni < 4; ++ni) rp[ni * 16] = acc[mi][ni][i];
    }
}

// ---------------- context GEMM (K-split) + ksum partials ----------------
__global__ __launch_bounds__(256) void k_ctx(
    const __hip_bfloat16* __restrict__ vfT, const __hip_bfloat16* __restrict__ kfT,
    float* __restrict__ ctxp, float* __restrict__ ksump) {
  __shared__ __align__(16) __bf16 As[4096], Bs[4096];
  const int z = blockIdx.z, h = z >> 2, kc = z & 3;
  const int tn = blockIdx.y << 7;
  const int t = threadIdx.x, w = t >> 6, lane = t & 63;
  const int m_off = (w >> 1) << 6, n_off = (w & 1) << 6;
  const int r0 = t >> 2, kk = (t & 3) << 3;
  char* Asb = (char*)As + (w << 10);
  char* Bsb = (char*)Bs + (w << 10);
  const int frow = lane & 15, koff = (lane >> 4) << 3;
  const __hip_bfloat16* A = vfT + ((size_t)h << 18) + (kc << 9);
  const __hip_bfloat16* B = kfT + ((size_t)h << 21) + (kc << 9);
  f32x4 acc[4][4];
  ZERO_ACC(acc);
  float bsum[4] = {0.f, 0.f, 0.f, 0.f};
  for (int k0 = 0; k0 < 512; k0 += 32) {
    const __hip_bfloat16* Ag = A + (size_t)r0 * 2048 + (k0 + kk);
    const __hip_bfloat16* Bg = B + (size_t)(tn + r0) * 2048 + (k0 + kk);
    gload16(Ag, Asb);
    gload16(Ag + (size_t)64 * 2048, Asb + 4096);
    gload16(Bg, Bsb);
    gload16(Bg + (size_t)64 * 2048, Bsb + 4096);
    __syncthreads();
    bf16x8 af[4], bfr[4];
#pragma unroll
    for (int mi = 0; mi < 4; ++mi)
      af[mi] = *(const bf16x8*)(As + ((m_off + mi * 16 + frow) << 5) + koff);
#pragma unroll
    for (int ni = 0; ni < 4; ++ni) {
      bfr[ni] = *(const bf16x8*)(Bs + ((n_off + ni * 16 + frow) << 5) + koff);
#pragma unroll
      for (int j = 0; j < 8; ++j) bsum[ni] += (float)bfr[ni][j];
    }
#pragma unroll
    for (int mi = 0; mi < 4; ++mi)
#pragma unroll
      for (int ni = 0; ni < 4; ++ni)
        acc[mi][ni] = __builtin_amdgcn_mfma_f32_16x16x32_bf16(af[mi], bfr[ni], acc[mi][ni], 0, 0, 0);
    __syncthreads();
  }
#pragma unroll
  for (int ni = 0; ni < 4; ++ni) {
    bsum[ni] += __shfl_xor(bsum[ni], 16);
    bsum[ni] += __shfl_xor(bsum[ni], 32);
  }
  if (w < 2 && (lane >> 4) == 0) {
#pragma unroll
    for (int ni = 0; ni < 4; ++ni)
      ksump[(((kc << 3) + h) << 10) + tn + n_off + ni * 16 + frow] = bsum[ni];
  }
  float* Cp = ctxp + ((size_t)((kc << 3) + h) << 17);
#pragma unroll
  for (int mi = 0; mi < 4; ++mi)
#pragma unroll
    for (int i = 0; i < 4; ++i) {
      const int row = m_off + mi * 16 + ((lane >> 4) << 2) + i;
#pragma unroll
      for (int ni = 0; ni < 4; ++ni) {
        const int col = tn + n_off + ni * 16 + frow;
        Cp[((size_t)row << 10) + col] = acc[mi][ni][i];
      }
    }
}

__global__ void k_ctxred(const float* __restrict__ ctxp, __hip_bfloat16* __restrict__ ctxT) {
  const int i = blockIdx.x * 256 + threadIdx.x;
  const float s = ctxp[i] + ctxp[i + 1048576] + ctxp[i + 2097152] + ctxp[i + 3145728];
  ctxT[i] = __float2bfloat16(s);
}

// ---------------- out GEMM + fused dinv + scatter ----------------
__global__ __launch_bounds__(256) void k_out(
    const __hip_bfloat16* __restrict__ qf, const __hip_bfloat16* __restrict__ ctxT,
    const float* __restrict__ ksump, float* __restrict__ outp) {
  __shared__ __align__(16) __bf16 As[4096], Bs[4096];
  __shared__ float ksum_s[1024];
  __shared__ float dsum_s[2][128];
  const int h = blockIdx.z;
  const int tm = blockIdx.x << 7;
  const int t = threadIdx.x, w = t >> 6, lane = t & 63;
  const int m_off = (w >> 1) << 6, n_off = (w & 1) << 6;
  const int r0 = t >> 2, kk = (t & 3) << 3;
  char* Asb = (char*)As + (w << 10);
  char* Bsb = (char*)Bs + (w << 10);
  const int frow = lane & 15, koff = (lane >> 4) << 3;
  const __hip_bfloat16* A = qf + ((size_t)h << 21);
  const __hip_bfloat16* B = ctxT + ((size_t)h << 17);
#pragma unroll
  for (int it = 0; it < 4; ++it) {
    const int d = t + it * 256;
    ksum_s[d] = ksump[(h << 10) + d] + ksump[((8 + h) << 10) + d] +
                ksump[((16 + h) << 10) + d] + ksump[((24 + h) << 10) + d];
  }
  f32x4 acc[4][4];
  ZERO_ACC(acc);
  const int drow = t & 127, dh = t >> 7;
  const int dsw = (drow >> 1) & 3;
  float dot = 0.f;
  for (int k0 = 0; k0 < 1024; k0 += 32) {
    const __hip_bfloat16* Ag = A + (size_t)(tm + r0) * 1024 + (k0 + kk);
    const __hip_bfloat16* Bg = B + (size_t)r0 * 1024 + (k0 + kk);
    gload16(Ag, Asb);
    gload16(Ag + (size_t)64 * 1024, Asb + 4096);
    gload16(Bg, Bsb);
    gload16(Bg + (size_t)64 * 1024, Bsb + 4096);
    __syncthreads();
    bf16x8 af[4], bfr[4];
#pragma unroll
    for (int mi = 0; mi < 4; ++mi)
      af[mi] = *(const bf16x8*)(As + ((m_off + mi * 16 + frow) << 5) + koff);
#pragma unroll
    for (int ni = 0; ni < 4; ++ni)
      bfr[ni] = *(const bf16x8*)(Bs + ((n_off + ni * 16 + frow) << 5) + koff);
#pragma unroll
    for (int u = 0; u < 2; ++u) {
      const int g = ((dh << 1) + u) ^ dsw;
      bf16x8 av = *(const bf16x8*)((char*)As + drow * 64 + g * 16);
      const float* kp = &ksum_s[k0 + (g << 3)];
#pragma unroll
      for (int j = 0; j < 8; ++j) dot += (float)av[j] * kp[j];
    }
#pragma unroll
    for (int mi = 0; mi < 4; ++mi)
#pragma unroll
      for (int ni = 0; ni < 4; ++ni)
        acc[mi][ni] = __builtin_amdgcn_mfma_f32_16x16x32_bf16(af[mi], bfr[ni], acc[mi][ni], 0, 0, 0);
    __syncthreads();
  }
  dsum_s[dh][drow] = dot;
  __syncthreads();
#pragma unroll
  for (int mi = 0; mi < 4; ++mi)
#pragma unroll
    for (int i = 0; i < 4; ++i) {
      const int rl = m_off + mi * 16 + ((lane >> 4) << 2) + i;
      const int row = tm + rl;
      const float dv = 1.0f / (dsum_s[0][rl] + dsum_s[1][rl]);
#pragma unroll
      for (int ni = 0; ni < 4; ++ni) {
        const int col = n_off + ni * 16 + frow;
        const int rb = col >> 4, tt = col & 15;
        outp[(((size_t)(rb << 11) + row) << 7) + (h << 4) + tt] = acc[mi][ni][i] * dv;
      }
    }
}

// ---------------- launch ----------------
extern "C" void kernel_launch(void* const* d_in, const int* in_sizes, int n_in,
                              void* d_out, int out_size, void* d_ws, size_t ws_size,
                              hipStream_t stream) {
  const float* x    = (const float*)d_in[0];
  const float* Wq   = (const float*)d_in[1];
  const float* bq   = (const float*)d_in[2];
  const float* Wk   = (const float*)d_in[3];
  const float* bk   = (const float*)d_in[4];
  const float* Wv   = (const float*)d_in[5];
  const float* bv   = (const float*)d_in[6];
  const float* proj = (const float*)d_in[7];
  if (ws_size < WS_NEED) return;

  char* ws = (char*)d_ws;
  __hip_bfloat16* xb   = (__hip_bfloat16*)(ws + OFF_XB);
  __hip_bfloat16* Wcat = (__hip_bfloat16*)(ws + OFF_WCAT);
  __hip_bfloat16* Mq   = (__hip_bfloat16*)(ws + OFF_MQ);
  __hip_bfloat16* Mk   = (__hip_bfloat16*)(ws + OFF_MK);
  float* bcat = (float*)(ws + OFF_BCAT);
  float* bqf  = (float*)(ws + OFF_BQF);
  float* bkf  = (float*)(ws + OFF_BKF);
  float* Y    = (float*)(ws + OFF_Y);
  __hip_bfloat16* qf  = (__hip_bfloat16*)(ws + OFF_QF);
  __hip_bfloat16* kf  = (__hip_bfloat16*)(ws + OFF_KF);
  __hip_bfloat16* kfT = (__hip_bfloat16*)(ws + OFF_KFT);
  __hip_bfloat16* vfT = (__hip_bfloat16*)(ws + OFF_VFT);
  unsigned* kmaxI = (unsigned*)(ws + OFF_KMAXI);
  float* ksump = (float*)(ws + OFF_KSUMP);
  _Float16* ek = (_Float16*)(ws + OFF_EK);
  float* ctxp  = (float*)(ws + OFF_CTXP);
  __hip_bfloat16* ctxT = (__hip_bfloat16*)(ws + OFF_CTXT);

  float* outp = (float*)d_out;
  float* attn = (float*)d_out + 2097152;

  static int attr_done = 0;
  if (!attr_done) {
    (void)hipFuncSetAttribute((const void*)k_attn8,
                              hipFuncAttributeMaxDynamicSharedMemorySize, 131072);
    attr_done = 1;
  }

  k_prep<<<dim3(2048), dim3(256), 0, stream>>>(x, Wq, bq, Wk, bk, Wv, bv, proj,
                                               xb, Wcat, bcat, Mq, Mk, bqf, bkf, kmaxI);
  k_proj<<<dim3(128, 3), dim3(256), 0, stream>>>(xb, Wcat, bcat, Y);
  k_vft2<<<dim3(16, 8, 8), dim3(256), 0, stream>>>(Y, vfT);
  k_dashq<<<dim3(128, 8), dim3(256), 0, stream>>>(xb, Mq, bqf, Y, qf);
  k_dashk_e<<<dim3(128, 8), dim3(256), 0, stream>>>(xb, Mk, bkf, Y, ek, kmaxI);
  k_kfeat<<<dim3(128, 8), dim3(256), 0, stream>>>(ek, kmaxI, kf, kfT);
  k_attn8<<<dim3(512), dim3(512), 131072, stream>>>(qf, kf, attn);
  k_ctx<<<dim3(1, 8, 32), dim3(256), 0, stream>>>(vfT, kfT, ctxp, ksump);
  k_ctxred<<<dim3(4096), dim3(256), 0, stream>>>(ctxp, ctxT);
  k_out<<<dim3(16, 1, 8), dim3(256), 0, stream>>>(qf, ctxT, ksump, outp);
}

// Round 7
// 205.849 us; speedup vs baseline: 1.1103x; 1.0832x over previous
//
#include <hip/hip_runtime.h>
#include <hip/hip_bf16.h>
#include <stdint.h>

typedef __bf16 bf16x8 __attribute__((ext_vector_type(8)));
typedef float  f32x4  __attribute__((ext_vector_type(4)));

#define RATIO 0.08838834764831845f
#define EPSV  1e-4f

#define GLOBAL_AS __attribute__((address_space(1)))
#define LDS_AS    __attribute__((address_space(3)))

static __device__ __forceinline__ void gload16(const void* g, void* l) {
  __builtin_amdgcn_global_load_lds((GLOBAL_AS const void*)g, (LDS_AS void*)l, 16, 0, 0);
}

// ---------------- workspace layout (bytes) ----------------
static constexpr size_t OFF_XB    = 0;                        // 16384*128*2
static constexpr size_t OFF_WCAT  = OFF_XB    + 4194304;      // 384*128*2
static constexpr size_t OFF_MQ    = OFF_WCAT  + 98304;        // 1024*128*2
static constexpr size_t OFF_MK    = OFF_MQ    + 262144;
static constexpr size_t OFF_BCAT  = OFF_MK    + 262144;       // 384*4 (pad)
static constexpr size_t OFF_BQF   = OFF_BCAT  + 2048;         // 1024*4
static constexpr size_t OFF_BKF   = OFF_BQF   + 4096;
static constexpr size_t OFF_Y     = OFF_BKF   + 4096;         // 16384*384*4
static constexpr size_t OFF_QF    = OFF_Y     + 25165824;     // 8*2048*1024*2
static constexpr size_t OFF_KF    = OFF_QF    + 33554432;
static constexpr size_t OFF_KFT   = OFF_KF    + 33554432;
static constexpr size_t OFF_VFT   = OFF_KFT   + 33554432;     // 8*128*2048*2
static constexpr size_t OFF_KPART = OFF_VFT   + 4194304;      // 8*128*4
static constexpr size_t OFF_KMAX  = OFF_KPART + 4096;         // 64*4
static constexpr size_t OFF_KSUM  = OFF_KMAX  + 256;          // 8*1024*4
static constexpr size_t OFF_DINV  = OFF_KSUM  + 32768;        // 16384*4
static constexpr size_t OFF_CTXP  = OFF_DINV  + 65536;        // 4*8*128*1024*4
static constexpr size_t OFF_CTXT  = OFF_CTXP  + 16777216;     // 8*128*1024*2
static constexpr size_t WS_NEED   = OFF_CTXT  + 2097152;

// ---------------- shared NT-GEMM core: C(128x128) = A(tm:,*) * B(tn:,*)^T ----
static __device__ __forceinline__ void gemm_core(
    const __hip_bfloat16* __restrict__ A, const __hip_bfloat16* __restrict__ B,
    int lda, int ldb, int K, int tm, int tn,
    __bf16* As, __bf16* Bs, f32x4 acc[4][4]) {
  const int t    = threadIdx.x;
  const int w    = t >> 6;
  const int lane = t & 63;
  const int m_off = (w >> 1) << 6;
  const int n_off = (w & 1) << 6;
  const int r0 = t >> 2;
  const int kk = (t & 3) << 3;
  char* Asb = (char*)As + (w << 10);
  char* Bsb = (char*)Bs + (w << 10);
  const int frow = lane & 15;
  const int koff = (lane >> 4) << 3;
  for (int k0 = 0; k0 < K; k0 += 32) {
    const __hip_bfloat16* Ag = A + (size_t)(tm + r0) * lda + (k0 + kk);
    const __hip_bfloat16* Bg = B + (size_t)(tn + r0) * ldb + (k0 + kk);
    gload16(Ag, Asb);
    gload16(Ag + (size_t)64 * lda, Asb + 4096);
    gload16(Bg, Bsb);
    gload16(Bg + (size_t)64 * ldb, Bsb + 4096);
    __syncthreads();
    bf16x8 af[4], bfr[4];
#pragma unroll
    for (int mi = 0; mi < 4; ++mi)
      af[mi] = *(const bf16x8*)(As + ((m_off + mi * 16 + frow) << 5) + koff);
#pragma unroll
    for (int ni = 0; ni < 4; ++ni)
      bfr[ni] = *(const bf16x8*)(Bs + ((n_off + ni * 16 + frow) << 5) + koff);
#pragma unroll
    for (int mi = 0; mi < 4; ++mi)
#pragma unroll
      for (int ni = 0; ni < 4; ++ni)
        acc[mi][ni] = __builtin_amdgcn_mfma_f32_16x16x32_bf16(af[mi], bfr[ni], acc[mi][ni], 0, 0, 0);
    __syncthreads();
  }
}

#define ZERO_ACC(acc) do {                                   \
  _Pragma("unroll") for (int a_ = 0; a_ < 4; ++a_)           \
  _Pragma("unroll") for (int b_ = 0; b_ < 4; ++b_)           \
    acc[a_][b_] = (f32x4){0.f, 0.f, 0.f, 0.f};               \
} while (0)

// ---------------- fused prep kernel ----------------
__global__ void k_prep(const float* __restrict__ x,
                       const float* __restrict__ Wq, const float* __restrict__ bq,
                       const float* __restrict__ Wk, const float* __restrict__ bk,
                       const float* __restrict__ Wv, const float* __restrict__ bv,
                       const float* __restrict__ proj,
                       __hip_bfloat16* __restrict__ xb,
                       __hip_bfloat16* __restrict__ Wcat, float* __restrict__ bcat,
                       __hip_bfloat16* __restrict__ Mq, __hip_bfloat16* __restrict__ Mk,
                       float* __restrict__ bqf, float* __restrict__ bkf) {
  const int b = blockIdx.x, t = threadIdx.x;
  { // convx: all 2048 blocks
    int i = (b * 256 + t) * 4;
    f32x4 v = *(const f32x4*)(x + i);
#pragma unroll
    for (int j = 0; j < 4; ++j) xb[i + j] = __float2bfloat16(v[j]);
  }
  if (b < 1024) { // prepM
    int i = b * 256 + t;
    {
      int which = i >> 17;
      int rem = i & 131071;
      int hj = rem >> 7, e = rem & 127;
      int hh = hj >> 7, j = hj & 127;
      const float* W = which ? Wk : Wq;
      float s = 0.f;
#pragma unroll
      for (int u = 0; u < 16; ++u) s += proj[j * 16 + u] * W[(hh * 16 + u) * 128 + e];
      if (which) Mk[rem] = __float2bfloat16(0.5f * s);
      else       Mq[rem] = __float2bfloat16(0.5f * s);
    }
    if (i < 2048) {
      int which = i >> 10;
      int hj = i & 1023, hh = hj >> 7, j = hj & 127;
      const float* bb = which ? bk : bq;
      float s = 0.f;
#pragma unroll
      for (int u = 0; u < 16; ++u) s += proj[j * 16 + u] * bb[hh * 16 + u];
      if (which) bkf[hj] = 0.5f * s;
      else       bqf[hj] = 0.5f * s;
    }
  }
  if (b < 192) { // prepwb
    int i = b * 256 + t;
    int mat = i >> 14, rem = i & 16383;
    const float* W = (mat == 0) ? Wq : ((mat == 1) ? Wk : Wv);
    Wcat[i] = __float2bfloat16(W[rem]);
    if (i < 384) {
      int m2 = i >> 7;
      const float* bb = (m2 == 0) ? bq : ((m2 == 1) ? bk : bv);
      bcat[i] = bb[i & 127];
    }
  }
}

// ---------------- projection GEMM: Y = x*Wcat^T + bcat ----------------
__global__ __launch_bounds__(256) void k_proj(
    const __hip_bfloat16* __restrict__ xb, const __hip_bfloat16* __restrict__ Wcat,
    const float* __restrict__ bcat, float* __restrict__ Y) {
  __shared__ __align__(16) __bf16 As[4096], Bs[4096];
  const int tm = blockIdx.x << 7, tn = blockIdx.y << 7;
  f32x4 acc[4][4];
  ZERO_ACC(acc);
  gemm_core(xb, Wcat, 128, 128, 128, tm, tn, As, Bs, acc);
  const int t = threadIdx.x, w = t >> 6, lane = t & 63;
  const int m_off = (w >> 1) << 6, n_off = (w & 1) << 6;
#pragma unroll
  for (int ni = 0; ni < 4; ++ni) {
    const int col = tn + n_off + ni * 16 + (lane & 15);
    const float bias = bcat[col];
#pragma unroll
    for (int mi = 0; mi < 4; ++mi)
#pragma unroll
      for (int i = 0; i < 4; ++i) {
        const int row = tm + m_off + mi * 16 + ((lane >> 4) << 2) + i;
        Y[(size_t)row * 384 + col] = acc[mi][ni][i] + bias;
      }
  }
}

// ---------------- vfT build (tiled transpose) ----------------
__global__ void k_vft2(const float* __restrict__ Y, __hip_bfloat16* __restrict__ vfT) {
  const int cb = blockIdx.x, r = blockIdx.y, h = blockIdx.z;
  const int c0 = cb << 7;
  __shared__ float tile[16][132];
  const int t = threadIdx.x;
  const int a = t & 15, cc0 = t >> 4;
#pragma unroll
  for (int i = 0; i < 8; ++i) {
    const int cc = cc0 + (i << 4);
    tile[a][cc] = Y[(size_t)(r * 2048 + c0 + cc) * 384 + 256 + (h << 4) + a];
  }
  __syncthreads();
  const int row = t >> 4, cg = t & 15;
  bf16x8 v;
#pragma unroll
  for (int j = 0; j < 8; ++j) v[j] = (__bf16)tile[row][(cg << 3) + j];
  *(bf16x8*)(vfT + ((size_t)((h << 7) + (r << 4) + row) << 11) + c0 + (cg << 3)) = v;
}

// ---------------- q features (r4 + coalesced qf write via LDS restage) -------
__global__ __launch_bounds__(256) void k_dashq(
    const __hip_bfloat16* __restrict__ xb, const __hip_bfloat16* __restrict__ Mq,
    const float* __restrict__ bqf, const float* __restrict__ Y,
    __hip_bfloat16* __restrict__ qf) {
  __shared__ __align__(16) char pool[34816];  // As(8K)+Bs(8K) during GEMM; qC[128][136] after
  __shared__ float diag_s[128];
  __shared__ float rmax_s[2][128];
  __bf16* As = (__bf16*)pool;
  __bf16* Bs = (__bf16*)(pool + 8192);
  __bf16* qC = (__bf16*)pool;
  const int h = blockIdx.y;
  const int tm = blockIdx.x << 7;
  f32x4 acc[4][4];
  ZERO_ACC(acc);
  const int t = threadIdx.x, w = t >> 6, lane = t & 63;
  if (t < 128) {
    const float* yp = Y + (size_t)(tm + t) * 384 + h * 16;
    float s = 0.f;
#pragma unroll
    for (int u = 0; u < 16; ++u) s += yp[u] * yp[u];
    diag_s[t] = 0.125f * s;
  }
  gemm_core(xb, Mq + h * 16384, 128, 128, 128, tm, 0, As, Bs, acc);
  const int m_off = (w >> 1) << 6, n_off = (w & 1) << 6;
  float bia[4];
#pragma unroll
  for (int ni = 0; ni < 4; ++ni) bia[ni] = bqf[h * 128 + n_off + ni * 16 + (lane & 15)];
  float rmx[4][4];
#pragma unroll
  for (int mi = 0; mi < 4; ++mi)
#pragma unroll
    for (int i = 0; i < 4; ++i) {
      float m0 = acc[mi][0][i] + bia[0];
      m0 = fmaxf(m0, acc[mi][1][i] + bia[1]);
      m0 = fmaxf(m0, acc[mi][2][i] + bia[2]);
      m0 = fmaxf(m0, acc[mi][3][i] + bia[3]);
      rmx[mi][i] = m0;
    }
#pragma unroll
  for (int off = 1; off < 16; off <<= 1)
#pragma unroll
    for (int mi = 0; mi < 4; ++mi)
#pragma unroll
      for (int i = 0; i < 4; ++i)
        rmx[mi][i] = fmaxf(rmx[mi][i], __shfl_xor(rmx[mi][i], off));
  if ((lane & 15) == 0) {
#pragma unroll
    for (int mi = 0; mi < 4; ++mi)
#pragma unroll
      for (int i = 0; i < 4; ++i)
        rmax_s[w & 1][m_off + mi * 16 + ((lane >> 4) << 2) + i] = rmx[mi][i];
  }
  __syncthreads();
  // compute features into qC (LDS), fragment layout
#pragma unroll
  for (int mi = 0; mi < 4; ++mi) {
#pragma unroll
    for (int i = 0; i < 4; ++i) {
      const int rl = m_off + mi * 16 + ((lane >> 4) << 2) + i;
      const float md = diag_s[rl] + fmaxf(rmax_s[0][rl], rmax_s[1][rl]);
#pragma unroll
      for (int ni = 0; ni < 4; ++ni) {
        const int j = n_off + ni * 16 + (lane & 15);
        const float f = RATIO * (__expf(acc[mi][ni][i] + bia[ni] - md) + EPSV);
        qC[rl * 136 + j] = (__bf16)f;
      }
    }
  }
  __syncthreads();
  // coalesced write: 256B contiguous per row, lane-contiguous
  const int r = tm >> 11, c0 = tm & 2047;
  const int cl0 = t >> 4, j0 = (t & 15) << 3;
#pragma unroll
  for (int p = 0; p < 8; ++p) {
    const int cl = cl0 + (p << 4);
    bf16x8 v = *(const bf16x8*)(qC + cl * 136 + j0);
    *(bf16x8*)((__bf16*)qf + (((size_t)((h << 11) + c0 + cl)) << 10) + (r << 7) + j0) = v;
  }
}

// ---------------- k features: pass A (max) ----------------
__global__ __launch_bounds__(256) void k_dashk_max(
    const __hip_bfloat16* __restrict__ xb, const __hip_bfloat16* __restrict__ Mk,
    const float* __restrict__ bkf, float* __restrict__ kpart) {
  __shared__ __align__(16) __bf16 As[4096], Bs[4096];
  __shared__ float wmax[4];
  const int h = blockIdx.y;
  const int tm = blockIdx.x << 7;
  f32x4 acc[4][4];
  ZERO_ACC(acc);
  gemm_core(xb, Mk + h * 16384, 128, 128, 128, tm, 0, As, Bs, acc);
  const int t = threadIdx.x, w = t >> 6, lane = t & 63;
  const int n_off = (w & 1) << 6;
  float mx = -1e30f;
#pragma unroll
  for (int ni = 0; ni < 4; ++ni) {
    const float bia = bkf[h * 128 + n_off + ni * 16 + (lane & 15)];
#pragma unroll
    for (int mi = 0; mi < 4; ++mi)
#pragma unroll
      for (int i = 0; i < 4; ++i) mx = fmaxf(mx, acc[mi][ni][i] + bia);
  }
#pragma unroll
  for (int off = 1; off < 64; off <<= 1) mx = fmaxf(mx, __shfl_xor(mx, off));
  if (lane == 0) wmax[w] = mx;
  __syncthreads();
  if (t == 0) kpart[h * 128 + blockIdx.x] = fmaxf(fmaxf(wmax[0], wmax[1]), fmaxf(wmax[2], wmax[3]));
}

__global__ void k_kmaxred(const float* __restrict__ kpart, float* __restrict__ kmax) {
  const int t = threadIdx.x;  // 64
  const int r = t >> 3, h = t & 7;
  float m = -1e30f;
  for (int i = 0; i < 16; ++i) m = fmaxf(m, kpart[h * 128 + r * 16 + i]);
  kmax[r * 8 + h] = m;
}

// ---------------- k features: pass B (features, kf + kfT) ----------------
__global__ __launch_bounds__(256) void k_dashk_feat(
    const __hip_bfloat16* __restrict__ xb, const __hip_bfloat16* __restrict__ Mk,
    const float* __restrict__ bkf, const float* __restrict__ Y,
    const float* __restrict__ kmax,
    __hip_bfloat16* __restrict__ kf, __hip_bfloat16* __restrict__ kfT) {
  __shared__ __align__(16) __bf16 As[4096], Bs[4096];
  __shared__ float diag_s[128];
  __shared__ __align__(16) __bf16 kT[128 * 136];
  const int h = blockIdx.y;
  const int tm = blockIdx.x << 7;
  f32x4 acc[4][4];
  ZERO_ACC(acc);
  gemm_core(xb, Mk + h * 16384, 128, 128, 128, tm, 0, As, Bs, acc);
  const int t = threadIdx.x, w = t >> 6, lane = t & 63;
  const int m_off = (w >> 1) << 6, n_off = (w & 1) << 6;
  if (t < 128) {
    const float* yp = Y + (size_t)(tm + t) * 384 + 128 + h * 16;
    float s = 0.f;
#pragma unroll
    for (int u = 0; u < 16; ++u) s += yp[u] * yp[u];
    diag_s[t] = 0.125f * s;
  }
  const int r = tm >> 11;
  const int c0 = tm & 2047;
  const float m = kmax[r * 8 + h];
  float bia[4];
#pragma unroll
  for (int ni = 0; ni < 4; ++ni) bia[ni] = bkf[h * 128 + n_off + ni * 16 + (lane & 15)];
  __syncthreads();
#pragma unroll
  for (int mi = 0; mi < 4; ++mi) {
#pragma unroll
    for (int i = 0; i < 4; ++i) {
      const int rl = m_off + mi * 16 + ((lane >> 4) << 2) + i;
      const int c = c0 + rl;
      const float dm = diag_s[rl] + m;
#pragma unroll
      for (int ni = 0; ni < 4; ++ni) {
        const int j = n_off + ni * 16 + (lane & 15);
        const float f = RATIO * (__expf(acc[mi][ni][i] + bia[ni] - dm) + EPSV);
        kf[((size_t)((h << 11) + c) << 10) + (r << 7) + j] = __float2bfloat16(f);
        kT[j * 136 + rl] = (__bf16)f;
      }
    }
  }
  __syncthreads();
  const int j2 = t >> 1, half = t & 1;
  __bf16* dst = (__bf16*)kfT + (((size_t)(h << 10) + (r << 7) + j2) << 11) + c0 + (half << 6);
  const __bf16* srcr = kT + j2 * 136 + (half << 6);
#pragma unroll
  for (int q8 = 0; q8 < 8; ++q8)
    *(bf16x8*)(dst + (q8 << 3)) = *(const bf16x8*)(srcr + (q8 << 3));
}

// ---------------- k_sum (row-reduce over kfT, coalesced) ----------------
__global__ __launch_bounds__(256) void k_ksum2(const __hip_bfloat16* __restrict__ kfT,
                                               float* __restrict__ ksum) {
  const int t = threadIdx.x, w = t >> 6, lane = t & 63;
  const int row = blockIdx.x * 4 + w;            // 0..8191 = h*1024 + d
  const __bf16* p = (const __bf16*)kfT + ((size_t)row << 11);
  float s = 0.f;
#pragma unroll
  for (int q = 0; q < 4; ++q) {
    bf16x8 v = *(const bf16x8*)(p + ((lane + (q << 6)) << 3));
#pragma unroll
    for (int j = 0; j < 8; ++j) s += (float)v[j];
  }
#pragma unroll
  for (int off = 1; off < 64; off <<= 1) s += __shfl_xor(s, off);
  if (lane == 0) ksum[row] = s;
}

__global__ __launch_bounds__(256) void k_dinv(
    const __hip_bfloat16* __restrict__ qf, const float* __restrict__ ksum,
    float* __restrict__ dinv) {
  const int t = threadIdx.x, w = t >> 6, lane = t & 63;
  const int h = blockIdx.y;
  const int c = blockIdx.x * 4 + w;
  const __bf16* qp = (const __bf16*)qf + ((size_t)((h << 11) + c) << 10);
  const float* ks = ksum + h * 1024;
  const int d0 = lane << 4;
  bf16x8 v0 = *(const bf16x8*)(qp + d0);
  bf16x8 v1 = *(const bf16x8*)(qp + d0 + 8);
  float s = 0.f;
#pragma unroll
  for (int j = 0; j < 8; ++j) s += (float)v0[j] * ks[d0 + j] + (float)v1[j] * ks[d0 + 8 + j];
#pragma unroll
  for (int off = 1; off < 64; off <<= 1) s += __shfl_xor(s, off);
  if (lane == 0) dinv[(h << 11) + c] = 1.0f / s;
}

// ---------------- attn GEMM: 256x256, BK=64, 2-phase/K-tile deep pipeline ----
#define SBAR() __builtin_amdgcn_s_barrier()
#define FEN()  do { asm volatile("" ::: "memory"); __builtin_amdgcn_sched_barrier(0); } while (0)
#define PRIO1() __builtin_amdgcn_s_setprio(1)
#define PRIO0() __builtin_amdgcn_s_setprio(0)
#define VMW4() do { asm volatile("s_waitcnt vmcnt(4)" ::: "memory"); } while (0)
#define VMW0() do { asm volatile("s_waitcnt vmcnt(0)" ::: "memory"); } while (0)

#define MFMA32() do {                                                         \
  _Pragma("unroll") for (int mi_ = 0; mi_ < 8; ++mi_)                         \
  _Pragma("unroll") for (int nj_ = 0; nj_ < 4; ++nj_)                         \
    acc[mi_][nj_] = __builtin_amdgcn_mfma_f32_16x16x32_bf16(                  \
        aR[mi_], bR[nj_], acc[mi_][nj_], 0, 0, 0);                            \
} while (0)

__global__ __launch_bounds__(512, 2) void k_attn8(
    const __hip_bfloat16* __restrict__ qf, const __hip_bfloat16* __restrict__ kf,
    float* __restrict__ attn) {
  extern __shared__ __align__(128) char lds[];
  const int lid = blockIdx.x;
  const int swz = ((lid & 7) << 6) + (lid >> 3);   // bijective XCD swizzle
  const int h  = swz >> 6;
  const int tm = ((swz >> 3) & 7) << 8;
  const int tn = (swz & 7) << 8;
  const __hip_bfloat16* Ag = qf + ((size_t)h << 21);
  const __hip_bfloat16* Bg = kf + ((size_t)h << 21);

  const int t = threadIdx.x, wid = t >> 6, lane = t & 63;
  const int f = lane & 15;
  const int wr = wid >> 2, wc = wid & 3;
  const int swzg = (((lane >> 4) ^ ((f >> 1) & 3)) << 4);   // read-side granule swizzle
  const int aoff = ((wr << 7) + f) * 64 + swzg;
  const int boff = 65536 + ((wc << 6) + f) * 64 + swzg;
  const int srow = t >> 2;
  const int scol = (((t & 3) ^ ((t >> 3) & 3)) << 3);       // inverse swizzle on global src
  const int sdst = wid << 10;

  f32x4 acc[8][4] = {};
  bf16x8 aR[8], bR[4];

  auto stageA = [&](int buf, int kh, int k0) {
    char* d = lds + buf * 32768 + kh * 16384 + sdst;
    const __hip_bfloat16* g = Ag + (size_t)(tm + srow) * 1024 + k0 + (kh << 5) + scol;
    gload16(g, d);
    gload16(g + 128 * 1024, d + 8192);
  };
  auto stageB = [&](int buf, int kh, int k0) {
    char* d = lds + 65536 + buf * 32768 + kh * 16384 + sdst;
    const __hip_bfloat16* g = Bg + (size_t)(tn + srow) * 1024 + k0 + (kh << 5) + scol;
    gload16(g, d);
    gload16(g + 128 * 1024, d + 8192);
  };

  // prologue: tile 0 -> buf0, order [Akh0,Bkh0,Akh1,Bkh1]
  stageA(0, 0, 0); stageB(0, 0, 0); stageA(0, 1, 0); stageB(0, 1, 0);
  VMW4();             // Akh0,Bkh0 resident
  SBAR(); FEN();

  for (int kt = 0; kt < 15; ++kt) {
    const int buf = kt & 1, nbuf = buf ^ 1;
    const int bo = buf * 32768;
    const int nk0 = (kt + 1) << 6;
    // phase A (kh0): stage kh0(t+1); wait completes kh1(this tile)
#pragma unroll
    for (int mi = 0; mi < 8; ++mi) aR[mi] = *(const bf16x8*)(lds + bo + aoff + mi * 1024);
#pragma unroll
    for (int nj = 0; nj < 4; ++nj) bR[nj] = *(const bf16x8*)(lds + bo + boff + nj * 1024);
    stageA(nbuf, 0, nk0);
    stageB(nbuf, 0, nk0);
    PRIO1(); MFMA32(); PRIO0();
    VMW4();
    SBAR(); FEN();
    // phase B (kh1): stage kh1(t+1); wait completes kh0(next tile)
#pragma unroll
    for (int mi = 0; mi < 8; ++mi) aR[mi] = *(const bf16x8*)(lds + bo + 16384 + aoff + mi * 1024);
#pragma unroll
    for (int nj = 0; nj < 4; ++nj) bR[nj] = *(const bf16x8*)(lds + bo + 16384 + boff + nj * 1024);
    stageA(nbuf, 1, nk0);
    stageB(nbuf, 1, nk0);
    PRIO1(); MFMA32(); PRIO0();
    VMW4();
    SBAR(); FEN();
  }
  { // epilogue: tile 15 in buf1
    const int bo = 32768;
#pragma unroll
    for (int mi = 0; mi < 8; ++mi) aR[mi] = *(const bf16x8*)(lds + bo + aoff + mi * 1024);
#pragma unroll
    for (int nj = 0; nj < 4; ++nj) bR[nj] = *(const bf16x8*)(lds + bo + boff + nj * 1024);
    PRIO1(); MFMA32(); PRIO0();
    VMW0();
    SBAR(); FEN();
#pragma unroll
    for (int mi = 0; mi < 8; ++mi) aR[mi] = *(const bf16x8*)(lds + bo + 16384 + aoff + mi * 1024);
#pragma unroll
    for (int nj = 0; nj < 4; ++nj) bR[nj] = *(const bf16x8*)(lds + bo + 16384 + boff + nj * 1024);
    PRIO1(); MFMA32(); PRIO0();
  }

  float* Cc = attn + ((size_t)h << 22);
  const int rbase = tm + (wr << 7) + ((lane >> 4) << 2);
  const int cbase = tn + (wc << 6) + f;
#pragma unroll
  for (int mi = 0; mi < 8; ++mi)
#pragma unroll
    for (int i = 0; i < 4; ++i) {
      float* rp = Cc + ((size_t)(rbase + mi * 16 + i) << 11) + cbase;
#pragma unroll
      for (int ni = 0; ni < 4; ++ni) rp[ni * 16] = acc[mi][ni][i];
    }
}

// ---------------- context GEMM (K-split) ----------------
__global__ __launch_bounds__(256) void k_ctx(
    const __hip_bfloat16* __restrict__ vfT, const __hip_bfloat16* __restrict__ kfT,
    float* __restrict__ ctxp) {
  __shared__ __align__(16) __bf16 As[4096], Bs[4096];
  const int z = blockIdx.z, h = z >> 2, kc = z & 3;
  const int tn = blockIdx.y << 7;
  f32x4 acc[4][4];
  ZERO_ACC(acc);
  gemm_core(vfT + ((size_t)h << 18) + (kc << 9), kfT + ((size_t)h << 21) + (kc << 9),
            2048, 2048, 512, 0, tn, As, Bs, acc);
  float* Cp = ctxp + ((size_t)(kc * 8 + h) << 17);
  const int t = threadIdx.x, w = t >> 6, lane = t & 63;
  const int m_off = (w >> 1) << 6, n_off = (w & 1) << 6;
#pragma unroll
  for (int mi = 0; mi < 4; ++mi)
#pragma unroll
    for (int i = 0; i < 4; ++i) {
      const int row = m_off + mi * 16 + ((lane >> 4) << 2) + i;
#pragma unroll
      for (int ni = 0; ni < 4; ++ni) {
        const int col = tn + n_off + ni * 16 + (lane & 15);
        Cp[((size_t)row << 10) + col] = acc[mi][ni][i];
      }
    }
}

__global__ void k_ctxred(const float* __restrict__ ctxp, __hip_bfloat16* __restrict__ ctxT) {
  const int i = blockIdx.x * 256 + threadIdx.x;
  const float s = ctxp[i] + ctxp[i + 1048576] + ctxp[i + 2097152] + ctxp[i + 3145728];
  ctxT[i] = __float2bfloat16(s);
}

// ---------------- out GEMM + D_inv scale + scatter ----------------
__global__ __launch_bounds__(256) void k_out(
    const __hip_bfloat16* __restrict__ qf, const __hip_bfloat16* __restrict__ ctxT,
    const float* __restrict__ dinv, float* __restrict__ outp) {
  __shared__ __align__(16) __bf16 As[4096], Bs[4096];
  const int h = blockIdx.z;
  const int tm = blockIdx.x << 7;
  f32x4 acc[4][4];
  ZERO_ACC(acc);
  gemm_core(qf + ((size_t)h << 21), ctxT + ((size_t)h << 17), 1024, 1024, 1024, tm, 0, As, Bs, acc);
  const int t = threadIdx.x, w = t >> 6, lane = t & 63;
  const int m_off = (w >> 1) << 6, n_off = (w & 1) << 6;
#pragma unroll
  for (int mi = 0; mi < 4; ++mi)
#pragma unroll
    for (int i = 0; i < 4; ++i) {
      const int row = tm + m_off + mi * 16 + ((lane >> 4) << 2) + i;
      const float dv = dinv[(h << 11) + row];
#pragma unroll
      for (int ni = 0; ni < 4; ++ni) {
        const int col = n_off + ni * 16 + (lane & 15);
        const int rb = col >> 4, tt = col & 15;
        outp[(((size_t)(rb << 11) + row) << 7) + (h << 4) + tt] = acc[mi][ni][i] * dv;
      }
    }
}

// ---------------- launch ----------------
extern "C" void kernel_launch(void* const* d_in, const int* in_sizes, int n_in,
                              void* d_out, int out_size, void* d_ws, size_t ws_size,
                              hipStream_t stream) {
  const float* x    = (const float*)d_in[0];
  const float* Wq   = (const float*)d_in[1];
  const float* bq   = (const float*)d_in[2];
  const float* Wk   = (const float*)d_in[3];
  const float* bk   = (const float*)d_in[4];
  const float* Wv   = (const float*)d_in[5];
  const float* bv   = (const float*)d_in[6];
  const float* proj = (const float*)d_in[7];
  if (ws_size < WS_NEED) return;

  char* ws = (char*)d_ws;
  __hip_bfloat16* xb   = (__hip_bfloat16*)(ws + OFF_XB);
  __hip_bfloat16* Wcat = (__hip_bfloat16*)(ws + OFF_WCAT);
  __hip_bfloat16* Mq   = (__hip_bfloat16*)(ws + OFF_MQ);
  __hip_bfloat16* Mk   = (__hip_bfloat16*)(ws + OFF_MK);
  float* bcat = (float*)(ws + OFF_BCAT);
  float* bqf  = (float*)(ws + OFF_BQF);
  float* bkf  = (float*)(ws + OFF_BKF);
  float* Y    = (float*)(ws + OFF_Y);
  __hip_bfloat16* qf  = (__hip_bfloat16*)(ws + OFF_QF);
  __hip_bfloat16* kf  = (__hip_bfloat16*)(ws + OFF_KF);
  __hip_bfloat16* kfT = (__hip_bfloat16*)(ws + OFF_KFT);
  __hip_bfloat16* vfT = (__hip_bfloat16*)(ws + OFF_VFT);
  float* kpart = (float*)(ws + OFF_KPART);
  float* kmax  = (float*)(ws + OFF_KMAX);
  float* ksum  = (float*)(ws + OFF_KSUM);
  float* dinv  = (float*)(ws + OFF_DINV);
  float* ctxp  = (float*)(ws + OFF_CTXP);
  __hip_bfloat16* ctxT = (__hip_bfloat16*)(ws + OFF_CTXT);

  float* outp = (float*)d_out;
  float* attn = (float*)d_out + 2097152;

  static int attr_done = 0;
  if (!attr_done) {
    (void)hipFuncSetAttribute((const void*)k_attn8,
                              hipFuncAttributeMaxDynamicSharedMemorySize, 131072);
    attr_done = 1;
  }

  k_prep<<<dim3(2048), dim3(256), 0, stream>>>(x, Wq, bq, Wk, bk, Wv, bv, proj,
                                               xb, Wcat, bcat, Mq, Mk, bqf, bkf);
  k_proj<<<dim3(128, 3), dim3(256), 0, stream>>>(xb, Wcat, bcat, Y);
  k_vft2<<<dim3(16, 8, 8), dim3(256), 0, stream>>>(Y, vfT);
  k_dashq<<<dim3(128, 8), dim3(256), 0, stream>>>(xb, Mq, bqf, Y, qf);
  k_dashk_max<<<dim3(128, 8), dim3(256), 0, stream>>>(xb, Mk, bkf, kpart);
  k_kmaxred<<<dim3(1), dim3(64), 0, stream>>>(kpart, kmax);
  k_dashk_feat<<<dim3(128, 8), dim3(256), 0, stream>>>(xb, Mk, bkf, Y, kmax, kf, kfT);
  k_ksum2<<<dim3(2048), dim3(256), 0, stream>>>(kfT, ksum);
  k_dinv<<<dim3(512, 8), dim3(256), 0, stream>>>(qf, ksum, dinv);
  k_attn8<<<dim3(512), dim3(512), 131072, stream>>>(qf, kf, attn);
  k_ctx<<<dim3(1, 8, 32), dim3(256), 0, stream>>>(vfT, kfT, ctxp);
  k_ctxred<<<dim3(4096), dim3(256), 0, stream>>>(ctxp, ctxT);
  k_out<<<dim3(16, 1, 8), dim3(256), 0, stream>>>(qf, ctxT, dinv, outp);
}

// Round 8
// 191.107 us; speedup vs baseline: 1.1960x; 1.0771x over previous
//
#include <hip/hip_runtime.h>
#include <hip/hip_bf16.h>
#include <stdint.h>

typedef __bf16 bf16x8 __attribute__((ext_vector_type(8)));
typedef float  f32x4  __attribute__((ext_vector_type(4)));

#define RATIO 0.08838834764831845f
#define EPSV  1e-4f

#define GLOBAL_AS __attribute__((address_space(1)))
#define LDS_AS    __attribute__((address_space(3)))

static __device__ __forceinline__ void gload16(const void* g, void* l) {
  __builtin_amdgcn_global_load_lds((GLOBAL_AS const void*)g, (LDS_AS void*)l, 16, 0, 0);
}

// ---------------- workspace layout (bytes) ----------------
static constexpr size_t OFF_XB    = 0;                        // 16384*128*2
static constexpr size_t OFF_WCAT  = OFF_XB    + 4194304;
static constexpr size_t OFF_MQ    = OFF_WCAT  + 98304;
static constexpr size_t OFF_MK    = OFF_MQ    + 262144;
static constexpr size_t OFF_BCAT  = OFF_MK    + 262144;
static constexpr size_t OFF_BQF   = OFF_BCAT  + 2048;
static constexpr size_t OFF_BKF   = OFF_BQF   + 4096;
static constexpr size_t OFF_Y     = OFF_BKF   + 4096;         // 16384*384*4
static constexpr size_t OFF_QF    = OFF_Y     + 25165824;     // 8*2048*1024*2
static constexpr size_t OFF_KF    = OFF_QF    + 33554432;
static constexpr size_t OFF_KFT   = OFF_KF    + 33554432;
static constexpr size_t OFF_VFT   = OFF_KFT   + 33554432;     // 8*128*2048*2
static constexpr size_t OFF_KPART = OFF_VFT   + 4194304;      // 8*128*4
static constexpr size_t OFF_KMAX  = OFF_KPART + 4096;         // 64*4 (pad 1024)
static constexpr size_t OFF_KSPART= OFF_KMAX  + 1024;         // 16*8*1024*4
static constexpr size_t OFF_DPART = OFF_KSPART+ 524288;       // 8*8*2048*4
static constexpr size_t OFF_CTXP  = OFF_DPART + 524288;       // 4*8*128*1024*4
static constexpr size_t OFF_CTXT  = OFF_CTXP  + 16777216;     // 8*128*1024*2
static constexpr size_t WS_NEED   = OFF_CTXT  + 2097152;

// ---------------- shared NT-GEMM core: C(128x128) = A(tm:,*) * B(tn:,*)^T ----
static __device__ __forceinline__ void gemm_core(
    const __hip_bfloat16* __restrict__ A, const __hip_bfloat16* __restrict__ B,
    int lda, int ldb, int K, int tm, int tn,
    __bf16* As, __bf16* Bs, f32x4 acc[4][4]) {
  const int t    = threadIdx.x;
  const int w    = t >> 6;
  const int lane = t & 63;
  const int m_off = (w >> 1) << 6;
  const int n_off = (w & 1) << 6;
  const int r0 = t >> 2;
  const int kk = (t & 3) << 3;
  char* Asb = (char*)As + (w << 10);
  char* Bsb = (char*)Bs + (w << 10);
  const int frow = lane & 15;
  const int koff = (lane >> 4) << 3;
  for (int k0 = 0; k0 < K; k0 += 32) {
    const __hip_bfloat16* Ag = A + (size_t)(tm + r0) * lda + (k0 + kk);
    const __hip_bfloat16* Bg = B + (size_t)(tn + r0) * ldb + (k0 + kk);
    gload16(Ag, Asb);
    gload16(Ag + (size_t)64 * lda, Asb + 4096);
    gload16(Bg, Bsb);
    gload16(Bg + (size_t)64 * ldb, Bsb + 4096);
    __syncthreads();
    bf16x8 af[4], bfr[4];
#pragma unroll
    for (int mi = 0; mi < 4; ++mi)
      af[mi] = *(const bf16x8*)(As + ((m_off + mi * 16 + frow) << 5) + koff);
#pragma unroll
    for (int ni = 0; ni < 4; ++ni)
      bfr[ni] = *(const bf16x8*)(Bs + ((n_off + ni * 16 + frow) << 5) + koff);
#pragma unroll
    for (int mi = 0; mi < 4; ++mi)
#pragma unroll
      for (int ni = 0; ni < 4; ++ni)
        acc[mi][ni] = __builtin_amdgcn_mfma_f32_16x16x32_bf16(af[mi], bfr[ni], acc[mi][ni], 0, 0, 0);
    __syncthreads();
  }
}

#define ZERO_ACC(acc) do {                                   \
  _Pragma("unroll") for (int a_ = 0; a_ < 4; ++a_)           \
  _Pragma("unroll") for (int b_ = 0; b_ < 4; ++b_)           \
    acc[a_][b_] = (f32x4){0.f, 0.f, 0.f, 0.f};               \
} while (0)

// ---------------- fused prep kernel ----------------
__global__ void k_prep(const float* __restrict__ x,
                       const float* __restrict__ Wq, const float* __restrict__ bq,
                       const float* __restrict__ Wk, const float* __restrict__ bk,
                       const float* __restrict__ Wv, const float* __restrict__ bv,
                       const float* __restrict__ proj,
                       __hip_bfloat16* __restrict__ xb,
                       __hip_bfloat16* __restrict__ Wcat, float* __restrict__ bcat,
                       __hip_bfloat16* __restrict__ Mq, __hip_bfloat16* __restrict__ Mk,
                       float* __restrict__ bqf, float* __restrict__ bkf) {
  const int b = blockIdx.x, t = threadIdx.x;
  { // convx: all 2048 blocks
    int i = (b * 256 + t) * 4;
    f32x4 v = *(const f32x4*)(x + i);
#pragma unroll
    for (int j = 0; j < 4; ++j) xb[i + j] = __float2bfloat16(v[j]);
  }
  if (b < 1024) { // prepM
    int i = b * 256 + t;
    {
      int which = i >> 17;
      int rem = i & 131071;
      int hj = rem >> 7, e = rem & 127;
      int hh = hj >> 7, j = hj & 127;
      const float* W = which ? Wk : Wq;
      float s = 0.f;
#pragma unroll
      for (int u = 0; u < 16; ++u) s += proj[j * 16 + u] * W[(hh * 16 + u) * 128 + e];
      if (which) Mk[rem] = __float2bfloat16(0.5f * s);
      else       Mq[rem] = __float2bfloat16(0.5f * s);
    }
    if (i < 2048) {
      int which = i >> 10;
      int hj = i & 1023, hh = hj >> 7, j = hj & 127;
      const float* bb = which ? bk : bq;
      float s = 0.f;
#pragma unroll
      for (int u = 0; u < 16; ++u) s += proj[j * 16 + u] * bb[hh * 16 + u];
      if (which) bkf[hj] = 0.5f * s;
      else       bqf[hj] = 0.5f * s;
    }
  }
  if (b < 192) { // prepwb
    int i = b * 256 + t;
    int mat = i >> 14, rem = i & 16383;
    const float* W = (mat == 0) ? Wq : ((mat == 1) ? Wk : Wv);
    Wcat[i] = __float2bfloat16(W[rem]);
    if (i < 384) {
      int m2 = i >> 7;
      const float* bb = (m2 == 0) ? bq : ((m2 == 1) ? bk : bv);
      bcat[i] = bb[i & 127];
    }
  }
}

// ---------------- projection GEMM: Y = x*Wcat^T + bcat; V-part -> vfT --------
__global__ __launch_bounds__(256) void k_proj(
    const __hip_bfloat16* __restrict__ xb, const __hip_bfloat16* __restrict__ Wcat,
    const float* __restrict__ bcat, float* __restrict__ Y,
    __hip_bfloat16* __restrict__ vfT) {
  __shared__ __align__(16) char pool[34816];  // As+Bs (16K) in GEMM; vT[128][136] bf16 after
  __bf16* As = (__bf16*)pool;
  __bf16* Bs = (__bf16*)(pool + 8192);
  const int tm = blockIdx.x << 7, tn = blockIdx.y << 7;
  f32x4 acc[4][4];
  ZERO_ACC(acc);
  gemm_core(xb, Wcat, 128, 128, 128, tm, tn, As, Bs, acc);
  const int t = threadIdx.x, w = t >> 6, lane = t & 63;
  const int m_off = (w >> 1) << 6, n_off = (w & 1) << 6;
  const int frow = lane & 15;
  if (tn == 256) {
    // V columns: write transposed bf16 directly into vfT (skip Y)
    __bf16* vT = (__bf16*)pool;  // gemm_core ends with __syncthreads(); LDS reusable
#pragma unroll
    for (int ni = 0; ni < 4; ++ni) {
      const int j = n_off + ni * 16 + frow;              // 0..127
      const float bias = bcat[256 + j];
#pragma unroll
      for (int mi = 0; mi < 4; ++mi)
#pragma unroll
        for (int i = 0; i < 4; ++i) {
          const int rl = m_off + mi * 16 + ((lane >> 4) << 2) + i;
          vT[j * 136 + rl] = (__bf16)(acc[mi][ni][i] + bias);
        }
    }
    __syncthreads();
    const int r = tm >> 11, c0 = tm & 2047;
    const int j2 = t >> 1, half = t & 1;
    const int hh = j2 >> 4, aa = j2 & 15;
    __bf16* dst = (__bf16*)vfT + (((size_t)(hh * 128 + r * 16 + aa)) << 11) + c0 + (half << 6);
    const __bf16* srcr = vT + j2 * 136 + (half << 6);
#pragma unroll
    for (int q8 = 0; q8 < 8; ++q8)
      *(bf16x8*)(dst + (q8 << 3)) = *(const bf16x8*)(srcr + (q8 << 3));
  } else {
#pragma unroll
    for (int ni = 0; ni < 4; ++ni) {
      const int col = tn + n_off + ni * 16 + frow;
      const float bias = bcat[col];
#pragma unroll
      for (int mi = 0; mi < 4; ++mi)
#pragma unroll
        for (int i = 0; i < 4; ++i) {
          const int row = tm + m_off + mi * 16 + ((lane >> 4) << 2) + i;
          Y[(size_t)row * 384 + col] = acc[mi][ni][i] + bias;
        }
    }
  }
}

// ---------------- k features: pass A (max) ----------------
__global__ __launch_bounds__(256) void k_dashk_max(
    const __hip_bfloat16* __restrict__ xb, const __hip_bfloat16* __restrict__ Mk,
    const float* __restrict__ bkf, float* __restrict__ kpart) {
  __shared__ __align__(16) __bf16 As[4096], Bs[4096];
  __shared__ float wmax[4];
  const int h = blockIdx.y;
  const int tm = blockIdx.x << 7;
  f32x4 acc[4][4];
  ZERO_ACC(acc);
  gemm_core(xb, Mk + h * 16384, 128, 128, 128, tm, 0, As, Bs, acc);
  const int t = threadIdx.x, w = t >> 6, lane = t & 63;
  const int n_off = (w & 1) << 6;
  float mx = -1e30f;
#pragma unroll
  for (int ni = 0; ni < 4; ++ni) {
    const float bia = bkf[h * 128 + n_off + ni * 16 + (lane & 15)];
#pragma unroll
    for (int mi = 0; mi < 4; ++mi)
#pragma unroll
      for (int i = 0; i < 4; ++i) mx = fmaxf(mx, acc[mi][ni][i] + bia);
  }
#pragma unroll
  for (int off = 1; off < 64; off <<= 1) mx = fmaxf(mx, __shfl_xor(mx, off));
  if (lane == 0) wmax[w] = mx;
  __syncthreads();
  if (t == 0) kpart[h * 128 + blockIdx.x] = fmaxf(fmaxf(wmax[0], wmax[1]), fmaxf(wmax[2], wmax[3]));
}

__global__ void k_kmaxred(const float* __restrict__ kpart, float* __restrict__ kmax) {
  const int t = threadIdx.x;  // 64
  const int r = t >> 3, h = t & 7;
  float m = -1e30f;
  for (int i = 0; i < 16; ++i) m = fmaxf(m, kpart[h * 128 + r * 16 + i]);
  kmax[r * 8 + h] = m;
}

// ---------------- k features: pass B (features, kf + kfT + ksum partials) ----
__global__ __launch_bounds__(256) void k_dashk_feat(
    const __hip_bfloat16* __restrict__ xb, const __hip_bfloat16* __restrict__ Mk,
    const float* __restrict__ bkf, const float* __restrict__ Y,
    const float* __restrict__ kmax,
    __hip_bfloat16* __restrict__ kf, __hip_bfloat16* __restrict__ kfT,
    float* __restrict__ kspart) {
  __shared__ __align__(16) __bf16 As[4096], Bs[4096];
  __shared__ float diag_s[128];
  __shared__ __align__(16) __bf16 kT[128 * 136];
  __shared__ float ksp_s[2][128];
  const int h = blockIdx.y;
  const int tm = blockIdx.x << 7;
  f32x4 acc[4][4];
  ZERO_ACC(acc);
  gemm_core(xb, Mk + h * 16384, 128, 128, 128, tm, 0, As, Bs, acc);
  const int t = threadIdx.x, w = t >> 6, lane = t & 63;
  const int m_off = (w >> 1) << 6, n_off = (w & 1) << 6;
  const int frow = lane & 15;
  if (t < 128) {
    const float* yp = Y + (size_t)(tm + t) * 384 + 128 + h * 16;
    float s = 0.f;
#pragma unroll
    for (int u = 0; u < 16; ++u) s += yp[u] * yp[u];
    diag_s[t] = 0.125f * s;
  }
  const int r = tm >> 11;
  const int c0 = tm & 2047;
  const int cb = blockIdx.x & 15;
  const float m = kmax[r * 8 + h];
  float bia[4];
#pragma unroll
  for (int ni = 0; ni < 4; ++ni) bia[ni] = bkf[h * 128 + n_off + ni * 16 + frow];
  float ksp[4] = {0.f, 0.f, 0.f, 0.f};
  __syncthreads();
#pragma unroll
  for (int mi = 0; mi < 4; ++mi) {
#pragma unroll
    for (int i = 0; i < 4; ++i) {
      const int rl = m_off + mi * 16 + ((lane >> 4) << 2) + i;
      const int c = c0 + rl;
      const float dm = diag_s[rl] + m;
#pragma unroll
      for (int ni = 0; ni < 4; ++ni) {
        const int j = n_off + ni * 16 + frow;
        const float f = RATIO * (__expf(acc[mi][ni][i] + bia[ni] - dm) + EPSV);
        const __hip_bfloat16 hb = __float2bfloat16(f);
        kf[((size_t)((h << 11) + c) << 10) + (r << 7) + j] = hb;
        kT[j * 136 + rl] = (__bf16)f;
        ksp[ni] += __bfloat162float(hb);
      }
    }
  }
  // ksum partials: reduce rows across lane-groups (g = lane>>4), then wave pairs
#pragma unroll
  for (int ni = 0; ni < 4; ++ni) {
    ksp[ni] += __shfl_xor(ksp[ni], 16);
    ksp[ni] += __shfl_xor(ksp[ni], 32);
  }
  if ((lane >> 4) == 0) {
#pragma unroll
    for (int ni = 0; ni < 4; ++ni)
      ksp_s[w >> 1][n_off + ni * 16 + frow] = ksp[ni];
  }
  __syncthreads();
  if (t < 128)
    kspart[(((cb << 3) + h) << 10) + r * 128 + t] = ksp_s[0][t] + ksp_s[1][t];
  const int j2 = t >> 1, half = t & 1;
  __bf16* dst = (__bf16*)kfT + (((size_t)(h << 10) + (r << 7) + j2) << 11) + c0 + (half << 6);
  const __bf16* srcr = kT + j2 * 136 + (half << 6);
#pragma unroll
  for (int q8 = 0; q8 < 8; ++q8)
    *(bf16x8*)(dst + (q8 << 3)) = *(const bf16x8*)(srcr + (q8 << 3));
}

// ---------------- q features (r4 epilogue + fused D_inv partial dot) ---------
__global__ __launch_bounds__(256) void k_dashq(
    const __hip_bfloat16* __restrict__ xb, const __hip_bfloat16* __restrict__ Mq,
    const float* __restrict__ bqf, const float* __restrict__ Y,
    const float* __restrict__ kspart,
    __hip_bfloat16* __restrict__ qf, float* __restrict__ dpart) {
  __shared__ __align__(16) __bf16 As[4096], Bs[4096];
  __shared__ float diag_s[128];
  __shared__ float rmax_s[2][128];
  __shared__ float ksum_s[128];
  __shared__ float dred_s[2][128];
  const int h = blockIdx.y;
  const int tm = blockIdx.x << 7;
  const int r = tm >> 11, c0 = tm & 2047;
  f32x4 acc[4][4];
  ZERO_ACC(acc);
  const int t = threadIdx.x, w = t >> 6, lane = t & 63;
  if (t < 128) {
    const float* yp = Y + (size_t)(tm + t) * 384 + h * 16;
    float s = 0.f;
#pragma unroll
    for (int u = 0; u < 16; ++u) s += yp[u] * yp[u];
    diag_s[t] = 0.125f * s;
    float ks = 0.f;
#pragma unroll
    for (int cb = 0; cb < 16; ++cb) ks += kspart[(((cb << 3) + h) << 10) + r * 128 + t];
    ksum_s[t] = ks;
  }
  gemm_core(xb, Mq + h * 16384, 128, 128, 128, tm, 0, As, Bs, acc);
  const int m_off = (w >> 1) << 6, n_off = (w & 1) << 6;
  const int frow = lane & 15;
  float bia[4];
#pragma unroll
  for (int ni = 0; ni < 4; ++ni) bia[ni] = bqf[h * 128 + n_off + ni * 16 + frow];
  float rmx[4][4];
#pragma unroll
  for (int mi = 0; mi < 4; ++mi)
#pragma unroll
    for (int i = 0; i < 4; ++i) {
      float m0 = acc[mi][0][i] + bia[0];
      m0 = fmaxf(m0, acc[mi][1][i] + bia[1]);
      m0 = fmaxf(m0, acc[mi][2][i] + bia[2]);
      m0 = fmaxf(m0, acc[mi][3][i] + bia[3]);
      rmx[mi][i] = m0;
    }
#pragma unroll
  for (int off = 1; off < 16; off <<= 1)
#pragma unroll
    for (int mi = 0; mi < 4; ++mi)
#pragma unroll
      for (int i = 0; i < 4; ++i)
        rmx[mi][i] = fmaxf(rmx[mi][i], __shfl_xor(rmx[mi][i], off));
  if (frow == 0) {
#pragma unroll
    for (int mi = 0; mi < 4; ++mi)
#pragma unroll
      for (int i = 0; i < 4; ++i)
        rmax_s[w & 1][m_off + mi * 16 + ((lane >> 4) << 2) + i] = rmx[mi][i];
  }
  __syncthreads();
  float p[4][4];
#pragma unroll
  for (int mi = 0; mi < 4; ++mi)
#pragma unroll
    for (int i = 0; i < 4; ++i) p[mi][i] = 0.f;
#pragma unroll
  for (int mi = 0; mi < 4; ++mi) {
#pragma unroll
    for (int i = 0; i < 4; ++i) {
      const int rl = m_off + mi * 16 + ((lane >> 4) << 2) + i;
      const float md = diag_s[rl] + fmaxf(rmax_s[0][rl], rmax_s[1][rl]);
#pragma unroll
      for (int ni = 0; ni < 4; ++ni) {
        const int j = n_off + ni * 16 + frow;
        const float f = RATIO * (__expf(acc[mi][ni][i] + bia[ni] - md) + EPSV);
        const __hip_bfloat16 hb = __float2bfloat16(f);
        qf[((size_t)((h << 11) + c0 + rl) << 10) + (r << 7) + j] = hb;
        p[mi][i] += __bfloat162float(hb) * ksum_s[j];
      }
    }
  }
  // reduce dot partials over the 16 frow lanes
#pragma unroll
  for (int off = 1; off < 16; off <<= 1)
#pragma unroll
    for (int mi = 0; mi < 4; ++mi)
#pragma unroll
      for (int i = 0; i < 4; ++i)
        p[mi][i] += __shfl_xor(p[mi][i], off);
  if (frow == 0) {
#pragma unroll
    for (int mi = 0; mi < 4; ++mi)
#pragma unroll
      for (int i = 0; i < 4; ++i)
        dred_s[w & 1][m_off + mi * 16 + ((lane >> 4) << 2) + i] = p[mi][i];
  }
  __syncthreads();
  if (t < 128)
    dpart[(((r << 3) + h) << 11) + c0 + t] = dred_s[0][t] + dred_s[1][t];
}

// ---------------- attn GEMM: 256x256, BK=64, 4-phase/K-tile (r4-exact) -------
#define SBAR() __builtin_amdgcn_s_barrier()
#define FEN()  do { asm volatile("" ::: "memory"); __builtin_amdgcn_sched_barrier(0); } while (0)
#define PRIO1() __builtin_amdgcn_s_setprio(1)
#define PRIO0() __builtin_amdgcn_s_setprio(0)
#define VMW4() do { asm volatile("s_waitcnt vmcnt(4)" ::: "memory"); } while (0)
#define VMW0() do { asm volatile("s_waitcnt vmcnt(0)" ::: "memory"); } while (0)

#define MFMA16(nlo) do {                                                      \
  _Pragma("unroll") for (int mi_ = 0; mi_ < 8; ++mi_)                         \
  _Pragma("unroll") for (int nj_ = 0; nj_ < 2; ++nj_)                         \
    acc[mi_][(nlo) + nj_] = __builtin_amdgcn_mfma_f32_16x16x32_bf16(          \
        aR[mi_], bR[nj_], acc[mi_][(nlo) + nj_], 0, 0, 0);                    \
} while (0)

__global__ __launch_bounds__(512, 2) void k_attn8(
    const __hip_bfloat16* __restrict__ qf, const __hip_bfloat16* __restrict__ kf,
    float* __restrict__ attn) {
  extern __shared__ __align__(128) char lds[];
  const int lid = blockIdx.x;
  const int swz = ((lid & 7) << 6) + (lid >> 3);
  const int h  = swz >> 6;
  const int tm = ((swz >> 3) & 7) << 8;
  const int tn = (swz & 7) << 8;
  const __hip_bfloat16* Ag = qf + ((size_t)h << 21);
  const __hip_bfloat16* Bg = kf + ((size_t)h << 21);

  const int t = threadIdx.x, wid = t >> 6, lane = t & 63;
  const int f = lane & 15;
  const int wr = wid >> 2, wc = wid & 3;
  const int swzg = (((lane >> 4) ^ ((f >> 1) & 3)) << 4);
  const int aoff = ((wr << 7) + f) * 64 + swzg;
  const int boff = 65536 + ((wc << 6) + f) * 64 + swzg;
  const int srow = t >> 2;
  const int scol = (((t & 3) ^ ((t >> 3) & 3)) << 3);
  const int sdst = wid << 10;

  f32x4 acc[8][4] = {};
  bf16x8 aR[8], bR[2];

  auto stageA = [&](int buf, int kh, int k0) {
    char* d = lds + buf * 32768 + kh * 16384 + sdst;
    const __hip_bfloat16* g = Ag + (size_t)(tm + srow) * 1024 + k0 + (kh << 5) + scol;
    gload16(g, d);
    gload16(g + 128 * 1024, d + 8192);
  };
  auto stageB = [&](int buf, int kh, int k0) {
    char* d = lds + 65536 + buf * 32768 + kh * 16384 + sdst;
    const __hip_bfloat16* g = Bg + (size_t)(tn + srow) * 1024 + k0 + (kh << 5) + scol;
    gload16(g, d);
    gload16(g + 128 * 1024, d + 8192);
  };

  stageA(0, 0, 0); stageB(0, 0, 0); stageA(0, 1, 0); stageB(0, 1, 0);
  VMW4();
  SBAR(); FEN();

  for (int kt = 0; kt < 15; ++kt) {
    const int buf = kt & 1, nbuf = buf ^ 1;
    const int bo = buf * 32768;
    const int nk0 = (kt + 1) << 6;
#pragma unroll
    for (int mi = 0; mi < 8; ++mi) aR[mi] = *(const bf16x8*)(lds + bo + aoff + mi * 1024);
    bR[0] = *(const bf16x8*)(lds + bo + boff);
    bR[1] = *(const bf16x8*)(lds + bo + boff + 1024);
    stageA(nbuf, 0, nk0);
    PRIO1(); MFMA16(0); PRIO0();
    SBAR(); FEN();
    bR[0] = *(const bf16x8*)(lds + bo + boff + 2048);
    bR[1] = *(const bf16x8*)(lds + bo + boff + 3072);
    stageB(nbuf, 0, nk0);
    PRIO1(); MFMA16(2); PRIO0();
    VMW4();
    SBAR(); FEN();
#pragma unroll
    for (int mi = 0; mi < 8; ++mi) aR[mi] = *(const bf16x8*)(lds + bo + 16384 + aoff + mi * 1024);
    bR[0] = *(const bf16x8*)(lds + bo + 16384 + boff);
    bR[1] = *(const bf16x8*)(lds + bo + 16384 + boff + 1024);
    stageA(nbuf, 1, nk0);
    PRIO1(); MFMA16(0); PRIO0();
    SBAR(); FEN();
    bR[0] = *(const bf16x8*)(lds + bo + 16384 + boff + 2048);
    bR[1] = *(const bf16x8*)(lds + bo + 16384 + boff + 3072);
    stageB(nbuf, 1, nk0);
    PRIO1(); MFMA16(2); PRIO0();
    VMW4();
    SBAR(); FEN();
  }
  {
    const int bo = 32768;
#pragma unroll
    for (int mi = 0; mi < 8; ++mi) aR[mi] = *(const bf16x8*)(lds + bo + aoff + mi * 1024);
    bR[0] = *(const bf16x8*)(lds + bo + boff);
    bR[1] = *(const bf16x8*)(lds + bo + boff + 1024);
    PRIO1(); MFMA16(0); PRIO0();
    bR[0] = *(const bf16x8*)(lds + bo + boff + 2048);
    bR[1] = *(const bf16x8*)(lds + bo + boff + 3072);
    PRIO1(); MFMA16(2); PRIO0();
    VMW0();
    SBAR(); FEN();
#pragma unroll
    for (int mi = 0; mi < 8; ++mi) aR[mi] = *(const bf16x8*)(lds + bo + 16384 + aoff + mi * 1024);
    bR[0] = *(const bf16x8*)(lds + bo + 16384 + boff);
    bR[1] = *(const bf16x8*)(lds + bo + 16384 + boff + 1024);
    PRIO1(); MFMA16(0); PRIO0();
    bR[0] = *(const bf16x8*)(lds + bo + 16384 + boff + 2048);
    bR[1] = *(const bf16x8*)(lds + bo + 16384 + boff + 3072);
    PRIO1(); MFMA16(2); PRIO0();
  }

  float* Cc = attn + ((size_t)h << 22);
  const int rbase = tm + (wr << 7) + ((lane >> 4) << 2);
  const int cbase = tn + (wc << 6) + f;
#pragma unroll
  for (int mi = 0; mi < 8; ++mi)
#pragma unroll
    for (int i = 0; i < 4; ++i) {
      float* rp = Cc + ((size_t)(rbase + mi * 16 + i) << 11) + cbase;
#pragma unroll
      for (int ni = 0; ni < 4; ++ni) rp[ni * 16] = acc[mi][ni][i];
    }
}

// ---------------- context GEMM (K-split) ----------------
__global__ __launch_bounds__(256) void k_ctx(
    const __hip_bfloat16* __restrict__ vfT, const __hip_bfloat16* __restrict__ kfT,
    float* __restrict__ ctxp) {
  __shared__ __align__(16) __bf16 As[4096], Bs[4096];
  const int z = blockIdx.z, h = z >> 2, kc = z & 3;
  const int tn = blockIdx.y << 7;
  f32x4 acc[4][4];
  ZERO_ACC(acc);
  gemm_core(vfT + ((size_t)h << 18) + (kc << 9), kfT + ((size_t)h << 21) + (kc << 9),
            2048, 2048, 512, 0, tn, As, Bs, acc);
  float* Cp = ctxp + ((size_t)(kc * 8 + h) << 17);
  const int t = threadIdx.x, w = t >> 6, lane = t & 63;
  const int m_off = (w >> 1) << 6, n_off = (w & 1) << 6;
#pragma unroll
  for (int mi = 0; mi < 4; ++mi)
#pragma unroll
    for (int i = 0; i < 4; ++i) {
      const int row = m_off + mi * 16 + ((lane >> 4) << 2) + i;
#pragma unroll
      for (int ni = 0; ni < 4; ++ni) {
        const int col = tn + n_off + ni * 16 + (lane & 15);
        Cp[((size_t)row << 10) + col] = acc[mi][ni][i];
      }
    }
}

__global__ void k_ctxred(const float* __restrict__ ctxp, __hip_bfloat16* __restrict__ ctxT) {
  const int i = blockIdx.x * 256 + threadIdx.x;
  const float s = ctxp[i] + ctxp[i + 1048576] + ctxp[i + 2097152] + ctxp[i + 3145728];
  ctxT[i] = __float2bfloat16(s);
}

// ---------------- out GEMM + D_inv (from dpart) + scatter ----------------
__global__ __launch_bounds__(256) void k_out(
    const __hip_bfloat16* __restrict__ qf, const __hip_bfloat16* __restrict__ ctxT,
    const float* __restrict__ dpart, float* __restrict__ outp) {
  __shared__ __align__(16) __bf16 As[4096], Bs[4096];
  __shared__ float dinv_s[128];
  const int h = blockIdx.z;
  const int tm = blockIdx.x << 7;
  const int t = threadIdx.x, w = t >> 6, lane = t & 63;
  if (t < 128) {
    float s = 0.f;
#pragma unroll
    for (int r = 0; r < 8; ++r) s += dpart[(((r << 3) + h) << 11) + tm + t];
    dinv_s[t] = 1.0f / s;
  }
  f32x4 acc[4][4];
  ZERO_ACC(acc);
  gemm_core(qf + ((size_t)h << 21), ctxT + ((size_t)h << 17), 1024, 1024, 1024, tm, 0, As, Bs, acc);
  const int m_off = (w >> 1) << 6, n_off = (w & 1) << 6;
#pragma unroll
  for (int mi = 0; mi < 4; ++mi)
#pragma unroll
    for (int i = 0; i < 4; ++i) {
      const int rl = m_off + mi * 16 + ((lane >> 4) << 2) + i;
      const int row = tm + rl;
      const float dv = dinv_s[rl];
#pragma unroll
      for (int ni = 0; ni < 4; ++ni) {
        const int col = n_off + ni * 16 + (lane & 15);
        const int rb = col >> 4, tt = col & 15;
        outp[(((size_t)(rb << 11) + row) << 7) + (h << 4) + tt] = acc[mi][ni][i] * dv;
      }
    }
}

// ---------------- launch ----------------
extern "C" void kernel_launch(void* const* d_in, const int* in_sizes, int n_in,
                              void* d_out, int out_size, void* d_ws, size_t ws_size,
                              hipStream_t stream) {
  const float* x    = (const float*)d_in[0];
  const float* Wq   = (const float*)d_in[1];
  const float* bq   = (const float*)d_in[2];
  const float* Wk   = (const float*)d_in[3];
  const float* bk   = (const float*)d_in[4];
  const float* Wv   = (const float*)d_in[5];
  const float* bv   = (const float*)d_in[6];
  const float* proj = (const float*)d_in[7];
  if (ws_size < WS_NEED) return;

  char* ws = (char*)d_ws;
  __hip_bfloat16* xb   = (__hip_bfloat16*)(ws + OFF_XB);
  __hip_bfloat16* Wcat = (__hip_bfloat16*)(ws + OFF_WCAT);
  __hip_bfloat16* Mq   = (__hip_bfloat16*)(ws + OFF_MQ);
  __hip_bfloat16* Mk   = (__hip_bfloat16*)(ws + OFF_MK);
  float* bcat = (float*)(ws + OFF_BCAT);
  float* bqf  = (float*)(ws + OFF_BQF);
  float* bkf  = (float*)(ws + OFF_BKF);
  float* Y    = (float*)(ws + OFF_Y);
  __hip_bfloat16* qf  = (__hip_bfloat16*)(ws + OFF_QF);
  __hip_bfloat16* kf  = (__hip_bfloat16*)(ws + OFF_KF);
  __hip_bfloat16* kfT = (__hip_bfloat16*)(ws + OFF_KFT);
  __hip_bfloat16* vfT = (__hip_bfloat16*)(ws + OFF_VFT);
  float* kpart  = (float*)(ws + OFF_KPART);
  float* kmax   = (float*)(ws + OFF_KMAX);
  float* kspart = (float*)(ws + OFF_KSPART);
  float* dpart  = (float*)(ws + OFF_DPART);
  float* ctxp   = (float*)(ws + OFF_CTXP);
  __hip_bfloat16* ctxT = (__hip_bfloat16*)(ws + OFF_CTXT);

  float* outp = (float*)d_out;
  float* attn = (float*)d_out + 2097152;

  static int attr_done = 0;
  if (!attr_done) {
    (void)hipFuncSetAttribute((const void*)k_attn8,
                              hipFuncAttributeMaxDynamicSharedMemorySize, 131072);
    attr_done = 1;
  }

  k_prep<<<dim3(2048), dim3(256), 0, stream>>>(x, Wq, bq, Wk, bk, Wv, bv, proj,
                                               xb, Wcat, bcat, Mq, Mk, bqf, bkf);
  k_proj<<<dim3(128, 3), dim3(256), 0, stream>>>(xb, Wcat, bcat, Y, vfT);
  k_dashk_max<<<dim3(128, 8), dim3(256), 0, stream>>>(xb, Mk, bkf, kpart);
  k_kmaxred<<<dim3(1), dim3(64), 0, stream>>>(kpart, kmax);
  k_dashk_feat<<<dim3(128, 8), dim3(256), 0, stream>>>(xb, Mk, bkf, Y, kmax, kf, kfT, kspart);
  k_dashq<<<dim3(128, 8), dim3(256), 0, stream>>>(xb, Mq, bqf, Y, kspart, qf, dpart);
  k_attn8<<<dim3(512), dim3(512), 131072, stream>>>(qf, kf, attn);
  k_ctx<<<dim3(1, 8, 32), dim3(256), 0, stream>>>(vfT, kfT, ctxp);
  k_ctxred<<<dim3(4096), dim3(256), 0, stream>>>(ctxp, ctxT);
  k_out<<<dim3(16, 1, 8), dim3(256), 0, stream>>>(qf, ctxT, dpart, outp);
}

// Round 9
// 183.637 us; speedup vs baseline: 1.2446x; 1.0407x over previous
//
#include <hip/hip_runtime.h>
#include <hip/hip_bf16.h>
#include <stdint.h>

typedef __bf16 bf16x8 __attribute__((ext_vector_type(8)));
typedef __bf16 bf16x4 __attribute__((ext_vector_type(4)));
typedef float  f32x4  __attribute__((ext_vector_type(4)));

#define RATIO 0.08838834764831845f
#define EPSV  1e-4f

#define GLOBAL_AS __attribute__((address_space(1)))
#define LDS_AS    __attribute__((address_space(3)))

static __device__ __forceinline__ void gload16(const void* g, void* l) {
  __builtin_amdgcn_global_load_lds((GLOBAL_AS const void*)g, (LDS_AS void*)l, 16, 0, 0);
}

// ---------------- workspace layout (bytes) ----------------
static constexpr size_t OFF_XB    = 0;                        // 16384*128*2
static constexpr size_t OFF_WCAT  = OFF_XB    + 4194304;
static constexpr size_t OFF_MQ    = OFF_WCAT  + 98304;
static constexpr size_t OFF_MK    = OFF_MQ    + 262144;
static constexpr size_t OFF_BCAT  = OFF_MK    + 262144;
static constexpr size_t OFF_BQF   = OFF_BCAT  + 2048;
static constexpr size_t OFF_BKF   = OFF_BQF   + 4096;
static constexpr size_t OFF_Y     = OFF_BKF   + 4096;         // 16384*384*4
static constexpr size_t OFF_QF    = OFF_Y     + 25165824;     // 8*2048*1024*2
static constexpr size_t OFF_KF    = OFF_QF    + 33554432;
static constexpr size_t OFF_KFT   = OFF_KF    + 33554432;
static constexpr size_t OFF_VFT   = OFF_KFT   + 33554432;     // 8*128*2048*2
static constexpr size_t OFF_KPART = OFF_VFT   + 4194304;      // 8*128*4
static constexpr size_t OFF_KMAX  = OFF_KPART + 4096;         // unused (pad)
static constexpr size_t OFF_KSPART= OFF_KMAX  + 1024;         // 16*8*1024*4
static constexpr size_t OFF_DPART = OFF_KSPART+ 524288;       // 8*8*2048*4
static constexpr size_t OFF_CTXP  = OFF_DPART + 524288;       // 4*8*128*1024*4
static constexpr size_t OFF_CTXT  = OFF_CTXP  + 16777216;     // 8*128*1024*2
static constexpr size_t WS_NEED   = OFF_CTXT  + 2097152;

// ---------------- shared NT-GEMM core: C(128x128) = A(tm:,*) * B(tn:,*)^T ----
static __device__ __forceinline__ void gemm_core(
    const __hip_bfloat16* __restrict__ A, const __hip_bfloat16* __restrict__ B,
    int lda, int ldb, int K, int tm, int tn,
    __bf16* As, __bf16* Bs, f32x4 acc[4][4]) {
  const int t    = threadIdx.x;
  const int w    = t >> 6;
  const int lane = t & 63;
  const int m_off = (w >> 1) << 6;
  const int n_off = (w & 1) << 6;
  const int r0 = t >> 2;
  const int kk = (t & 3) << 3;
  char* Asb = (char*)As + (w << 10);
  char* Bsb = (char*)Bs + (w << 10);
  const int frow = lane & 15;
  const int koff = (lane >> 4) << 3;
  for (int k0 = 0; k0 < K; k0 += 32) {
    const __hip_bfloat16* Ag = A + (size_t)(tm + r0) * lda + (k0 + kk);
    const __hip_bfloat16* Bg = B + (size_t)(tn + r0) * ldb + (k0 + kk);
    gload16(Ag, Asb);
    gload16(Ag + (size_t)64 * lda, Asb + 4096);
    gload16(Bg, Bsb);
    gload16(Bg + (size_t)64 * ldb, Bsb + 4096);
    __syncthreads();
    bf16x8 af[4], bfr[4];
#pragma unroll
    for (int mi = 0; mi < 4; ++mi)
      af[mi] = *(const bf16x8*)(As + ((m_off + mi * 16 + frow) << 5) + koff);
#pragma unroll
    for (int ni = 0; ni < 4; ++ni)
      bfr[ni] = *(const bf16x8*)(Bs + ((n_off + ni * 16 + frow) << 5) + koff);
#pragma unroll
    for (int mi = 0; mi < 4; ++mi)
#pragma unroll
      for (int ni = 0; ni < 4; ++ni)
        acc[mi][ni] = __builtin_amdgcn_mfma_f32_16x16x32_bf16(af[mi], bfr[ni], acc[mi][ni], 0, 0, 0);
    __syncthreads();
  }
}

#define ZERO_ACC(acc) do {                                   \
  _Pragma("unroll") for (int a_ = 0; a_ < 4; ++a_)           \
  _Pragma("unroll") for (int b_ = 0; b_ < 4; ++b_)           \
    acc[a_][b_] = (f32x4){0.f, 0.f, 0.f, 0.f};               \
} while (0)

// ---------------- fused prep kernel ----------------
__global__ void k_prep(const float* __restrict__ x,
                       const float* __restrict__ Wq, const float* __restrict__ bq,
                       const float* __restrict__ Wk, const float* __restrict__ bk,
                       const float* __restrict__ Wv, const float* __restrict__ bv,
                       const float* __restrict__ proj,
                       __hip_bfloat16* __restrict__ xb,
                       __hip_bfloat16* __restrict__ Wcat, float* __restrict__ bcat,
                       __hip_bfloat16* __restrict__ Mq, __hip_bfloat16* __restrict__ Mk,
                       float* __restrict__ bqf, float* __restrict__ bkf) {
  const int b = blockIdx.x, t = threadIdx.x;
  { // convx: all 2048 blocks
    int i = (b * 256 + t) * 4;
    f32x4 v = *(const f32x4*)(x + i);
#pragma unroll
    for (int j = 0; j < 4; ++j) xb[i + j] = __float2bfloat16(v[j]);
  }
  if (b < 1024) { // prepM
    int i = b * 256 + t;
    {
      int which = i >> 17;
      int rem = i & 131071;
      int hj = rem >> 7, e = rem & 127;
      int hh = hj >> 7, j = hj & 127;
      const float* W = which ? Wk : Wq;
      float s = 0.f;
#pragma unroll
      for (int u = 0; u < 16; ++u) s += proj[j * 16 + u] * W[(hh * 16 + u) * 128 + e];
      if (which) Mk[rem] = __float2bfloat16(0.5f * s);
      else       Mq[rem] = __float2bfloat16(0.5f * s);
    }
    if (i < 2048) {
      int which = i >> 10;
      int hj = i & 1023, hh = hj >> 7, j = hj & 127;
      const float* bb = which ? bk : bq;
      float s = 0.f;
#pragma unroll
      for (int u = 0; u < 16; ++u) s += proj[j * 16 + u] * bb[hh * 16 + u];
      if (which) bkf[hj] = 0.5f * s;
      else       bqf[hj] = 0.5f * s;
    }
  }
  if (b < 192) { // prepwb
    int i = b * 256 + t;
    int mat = i >> 14, rem = i & 16383;
    const float* W = (mat == 0) ? Wq : ((mat == 1) ? Wk : Wv);
    Wcat[i] = __float2bfloat16(W[rem]);
    if (i < 384) {
      int m2 = i >> 7;
      const float* bb = (m2 == 0) ? bq : ((m2 == 1) ? bk : bv);
      bcat[i] = bb[i & 127];
    }
  }
}

// ---------------- projection GEMM: Y = x*Wcat^T + bcat; V-part -> vfT --------
__global__ __launch_bounds__(256) void k_proj(
    const __hip_bfloat16* __restrict__ xb, const __hip_bfloat16* __restrict__ Wcat,
    const float* __restrict__ bcat, float* __restrict__ Y,
    __hip_bfloat16* __restrict__ vfT) {
  __shared__ __align__(16) char pool[34816];
  __bf16* As = (__bf16*)pool;
  __bf16* Bs = (__bf16*)(pool + 8192);
  const int tm = blockIdx.x << 7, tn = blockIdx.y << 7;
  f32x4 acc[4][4];
  ZERO_ACC(acc);
  gemm_core(xb, Wcat, 128, 128, 128, tm, tn, As, Bs, acc);
  const int t = threadIdx.x, w = t >> 6, lane = t & 63;
  const int m_off = (w >> 1) << 6, n_off = (w & 1) << 6;
  const int frow = lane & 15;
  if (tn == 256) {
    __bf16* vT = (__bf16*)pool;
#pragma unroll
    for (int ni = 0; ni < 4; ++ni) {
      const int j = n_off + ni * 16 + frow;
      const float bias = bcat[256 + j];
#pragma unroll
      for (int mi = 0; mi < 4; ++mi)
#pragma unroll
        for (int i = 0; i < 4; ++i) {
          const int rl = m_off + mi * 16 + ((lane >> 4) << 2) + i;
          vT[j * 136 + rl] = (__bf16)(acc[mi][ni][i] + bias);
        }
    }
    __syncthreads();
    const int r = tm >> 11, c0 = tm & 2047;
    const int j2 = t >> 1, half = t & 1;
    const int hh = j2 >> 4, aa = j2 & 15;
    __bf16* dst = (__bf16*)vfT + (((size_t)(hh * 128 + r * 16 + aa)) << 11) + c0 + (half << 6);
    const __bf16* srcr = vT + j2 * 136 + (half << 6);
#pragma unroll
    for (int q8 = 0; q8 < 8; ++q8)
      *(bf16x8*)(dst + (q8 << 3)) = *(const bf16x8*)(srcr + (q8 << 3));
  } else {
#pragma unroll
    for (int ni = 0; ni < 4; ++ni) {
      const int col = tn + n_off + ni * 16 + frow;
      const float bias = bcat[col];
#pragma unroll
      for (int mi = 0; mi < 4; ++mi)
#pragma unroll
        for (int i = 0; i < 4; ++i) {
          const int row = tm + m_off + mi * 16 + ((lane >> 4) << 2) + i;
          Y[(size_t)row * 384 + col] = acc[mi][ni][i] + bias;
        }
    }
  }
}

// ---------------- k features: pass A (max) ----------------
__global__ __launch_bounds__(256) void k_dashk_max(
    const __hip_bfloat16* __restrict__ xb, const __hip_bfloat16* __restrict__ Mk,
    const float* __restrict__ bkf, float* __restrict__ kpart) {
  __shared__ __align__(16) __bf16 As[4096], Bs[4096];
  __shared__ float wmax[4];
  const int h = blockIdx.y;
  const int tm = blockIdx.x << 7;
  f32x4 acc[4][4];
  ZERO_ACC(acc);
  gemm_core(xb, Mk + h * 16384, 128, 128, 128, tm, 0, As, Bs, acc);
  const int t = threadIdx.x, w = t >> 6, lane = t & 63;
  const int n_off = (w & 1) << 6;
  float mx = -1e30f;
#pragma unroll
  for (int ni = 0; ni < 4; ++ni) {
    const float bia = bkf[h * 128 + n_off + ni * 16 + (lane & 15)];
#pragma unroll
    for (int mi = 0; mi < 4; ++mi)
#pragma unroll
      for (int i = 0; i < 4; ++i) mx = fmaxf(mx, acc[mi][ni][i] + bia);
  }
#pragma unroll
  for (int off = 1; off < 64; off <<= 1) mx = fmaxf(mx, __shfl_xor(mx, off));
  if (lane == 0) wmax[w] = mx;
  __syncthreads();
  if (t == 0) kpart[h * 128 + blockIdx.x] = fmaxf(fmaxf(wmax[0], wmax[1]), fmaxf(wmax[2], wmax[3]));
}

// ---------------- k features: pass B (features, kf + kfT + ksum partials) ----
__global__ __launch_bounds__(256) void k_dashk_feat(
    const __hip_bfloat16* __restrict__ xb, const __hip_bfloat16* __restrict__ Mk,
    const float* __restrict__ bkf, const float* __restrict__ Y,
    const float* __restrict__ kpart,
    __hip_bfloat16* __restrict__ kf, __hip_bfloat16* __restrict__ kfT,
    float* __restrict__ kspart) {
  __shared__ __align__(16) __bf16 As[4096], Bs[4096];
  __shared__ float diag_s[128];
  __shared__ __align__(16) __bf16 kT[128 * 136];
  __shared__ float ksp_s[2][128];
  const int h = blockIdx.y;
  const int tm = blockIdx.x << 7;
  f32x4 acc[4][4];
  ZERO_ACC(acc);
  gemm_core(xb, Mk + h * 16384, 128, 128, 128, tm, 0, As, Bs, acc);
  const int t = threadIdx.x, w = t >> 6, lane = t & 63;
  const int m_off = (w >> 1) << 6, n_off = (w & 1) << 6;
  const int frow = lane & 15;
  if (t < 128) {
    const float* yp = Y + (size_t)(tm + t) * 384 + 128 + h * 16;
    float s = 0.f;
#pragma unroll
    for (int u = 0; u < 16; ++u) s += yp[u] * yp[u];
    diag_s[t] = 0.125f * s;
  }
  const int r = tm >> 11;
  const int c0 = tm & 2047;
  const int cb = blockIdx.x & 15;
  // inline kmax reduce (absorbed k_kmaxred): max over the 16 blocks of this r
  float m = -1e30f;
  {
    const float* kp = kpart + h * 128 + r * 16;
#pragma unroll
    for (int i = 0; i < 16; ++i) m = fmaxf(m, kp[i]);
  }
  float bia[4];
#pragma unroll
  for (int ni = 0; ni < 4; ++ni) bia[ni] = bkf[h * 128 + n_off + ni * 16 + frow];
  float ksp[4] = {0.f, 0.f, 0.f, 0.f};
  __syncthreads();
#pragma unroll
  for (int mi = 0; mi < 4; ++mi) {
#pragma unroll
    for (int i = 0; i < 4; ++i) {
      const int rl = m_off + mi * 16 + ((lane >> 4) << 2) + i;
      const int c = c0 + rl;
      const float dm = diag_s[rl] + m;
#pragma unroll
      for (int ni = 0; ni < 4; ++ni) {
        const int j = n_off + ni * 16 + frow;
        const float f = RATIO * (__expf(acc[mi][ni][i] + bia[ni] - dm) + EPSV);
        const __hip_bfloat16 hb = __float2bfloat16(f);
        kf[((size_t)((h << 11) + c) << 10) + (r << 7) + j] = hb;
        kT[j * 136 + rl] = (__bf16)f;
        ksp[ni] += __bfloat162float(hb);
      }
    }
  }
#pragma unroll
  for (int ni = 0; ni < 4; ++ni) {
    ksp[ni] += __shfl_xor(ksp[ni], 16);
    ksp[ni] += __shfl_xor(ksp[ni], 32);
  }
  if ((lane >> 4) == 0) {
#pragma unroll
    for (int ni = 0; ni < 4; ++ni)
      ksp_s[w >> 1][n_off + ni * 16 + frow] = ksp[ni];
  }
  __syncthreads();
  if (t < 128)
    kspart[(((cb << 3) + h) << 10) + r * 128 + t] = ksp_s[0][t] + ksp_s[1][t];
  const int j2 = t >> 1, half = t & 1;
  __bf16* dst = (__bf16*)kfT + (((size_t)(h << 10) + (r << 7) + j2) << 11) + c0 + (half << 6);
  const __bf16* srcr = kT + j2 * 136 + (half << 6);
#pragma unroll
  for (int q8 = 0; q8 < 8; ++q8)
    *(bf16x8*)(dst + (q8 << 3)) = *(const bf16x8*)(srcr + (q8 << 3));
}

// ---------------- q features (r4 epilogue + fused D_inv partial dot) ---------
__global__ __launch_bounds__(256) void k_dashq(
    const __hip_bfloat16* __restrict__ xb, const __hip_bfloat16* __restrict__ Mq,
    const float* __restrict__ bqf, const float* __restrict__ Y,
    const float* __restrict__ kspart,
    __hip_bfloat16* __restrict__ qf, float* __restrict__ dpart) {
  __shared__ __align__(16) __bf16 As[4096], Bs[4096];
  __shared__ float diag_s[128];
  __shared__ float rmax_s[2][128];
  __shared__ float ksum_s[128];
  __shared__ float dred_s[2][128];
  const int h = blockIdx.y;
  const int tm = blockIdx.x << 7;
  const int r = tm >> 11, c0 = tm & 2047;
  f32x4 acc[4][4];
  ZERO_ACC(acc);
  const int t = threadIdx.x, w = t >> 6, lane = t & 63;
  if (t < 128) {
    const float* yp = Y + (size_t)(tm + t) * 384 + h * 16;
    float s = 0.f;
#pragma unroll
    for (int u = 0; u < 16; ++u) s += yp[u] * yp[u];
    diag_s[t] = 0.125f * s;
    float ks = 0.f;
#pragma unroll
    for (int cb = 0; cb < 16; ++cb) ks += kspart[(((cb << 3) + h) << 10) + r * 128 + t];
    ksum_s[t] = ks;
  }
  gemm_core(xb, Mq + h * 16384, 128, 128, 128, tm, 0, As, Bs, acc);
  const int m_off = (w >> 1) << 6, n_off = (w & 1) << 6;
  const int frow = lane & 15;
  float bia[4];
#pragma unroll
  for (int ni = 0; ni < 4; ++ni) bia[ni] = bqf[h * 128 + n_off + ni * 16 + frow];
  float rmx[4][4];
#pragma unroll
  for (int mi = 0; mi < 4; ++mi)
#pragma unroll
    for (int i = 0; i < 4; ++i) {
      float m0 = acc[mi][0][i] + bia[0];
      m0 = fmaxf(m0, acc[mi][1][i] + bia[1]);
      m0 = fmaxf(m0, acc[mi][2][i] + bia[2]);
      m0 = fmaxf(m0, acc[mi][3][i] + bia[3]);
      rmx[mi][i] = m0;
    }
#pragma unroll
  for (int off = 1; off < 16; off <<= 1)
#pragma unroll
    for (int mi = 0; mi < 4; ++mi)
#pragma unroll
      for (int i = 0; i < 4; ++i)
        rmx[mi][i] = fmaxf(rmx[mi][i], __shfl_xor(rmx[mi][i], off));
  if (frow == 0) {
#pragma unroll
    for (int mi = 0; mi < 4; ++mi)
#pragma unroll
      for (int i = 0; i < 4; ++i)
        rmax_s[w & 1][m_off + mi * 16 + ((lane >> 4) << 2) + i] = rmx[mi][i];
  }
  __syncthreads();
  float p[4][4];
#pragma unroll
  for (int mi = 0; mi < 4; ++mi)
#pragma unroll
    for (int i = 0; i < 4; ++i) p[mi][i] = 0.f;
#pragma unroll
  for (int mi = 0; mi < 4; ++mi) {
#pragma unroll
    for (int i = 0; i < 4; ++i) {
      const int rl = m_off + mi * 16 + ((lane >> 4) << 2) + i;
      const float md = diag_s[rl] + fmaxf(rmax_s[0][rl], rmax_s[1][rl]);
#pragma unroll
      for (int ni = 0; ni < 4; ++ni) {
        const int j = n_off + ni * 16 + frow;
        const float f = RATIO * (__expf(acc[mi][ni][i] + bia[ni] - md) + EPSV);
        const __hip_bfloat16 hb = __float2bfloat16(f);
        qf[((size_t)((h << 11) + c0 + rl) << 10) + (r << 7) + j] = hb;
        p[mi][i] += __bfloat162float(hb) * ksum_s[j];
      }
    }
  }
#pragma unroll
  for (int off = 1; off < 16; off <<= 1)
#pragma unroll
    for (int mi = 0; mi < 4; ++mi)
#pragma unroll
      for (int i = 0; i < 4; ++i)
        p[mi][i] += __shfl_xor(p[mi][i], off);
  if (frow == 0) {
#pragma unroll
    for (int mi = 0; mi < 4; ++mi)
#pragma unroll
      for (int i = 0; i < 4; ++i)
        dred_s[w & 1][m_off + mi * 16 + ((lane >> 4) << 2) + i] = p[mi][i];
  }
  __syncthreads();
  if (t < 128)
    dpart[(((r << 3) + h) << 11) + c0 + t] = dred_s[0][t] + dred_s[1][t];
}

// ---------------- attn GEMM: 256x256, BK=64, 4-phase (lockstep barriers cut) -
#define SBAR() __builtin_amdgcn_s_barrier()
#define FEN()  do { asm volatile("" ::: "memory"); __builtin_amdgcn_sched_barrier(0); } while (0)
#define PRIO1() __builtin_amdgcn_s_setprio(1)
#define PRIO0() __builtin_amdgcn_s_setprio(0)
#define VMW4() do { asm volatile("s_waitcnt vmcnt(4)" ::: "memory"); } while (0)
#define VMW0() do { asm volatile("s_waitcnt vmcnt(0)" ::: "memory"); } while (0)

#define MFMA16(nlo) do {                                                      \
  _Pragma("unroll") for (int mi_ = 0; mi_ < 8; ++mi_)                         \
  _Pragma("unroll") for (int nj_ = 0; nj_ < 2; ++nj_)                         \
    acc[mi_][(nlo) + nj_] = __builtin_amdgcn_mfma_f32_16x16x32_bf16(          \
        aR[mi_], bR[nj_], acc[mi_][(nlo) + nj_], 0, 0, 0);                    \
} while (0)

__global__ __launch_bounds__(512, 2) void k_attn8(
    const __hip_bfloat16* __restrict__ qf, const __hip_bfloat16* __restrict__ kf,
    float* __restrict__ attn) {
  extern __shared__ __align__(128) char lds[];
  const int lid = blockIdx.x;
  const int swz = ((lid & 7) << 6) + (lid >> 3);
  const int h  = swz >> 6;
  const int tm = ((swz >> 3) & 7) << 8;
  const int tn = (swz & 7) << 8;
  const __hip_bfloat16* Ag = qf + ((size_t)h << 21);
  const __hip_bfloat16* Bg = kf + ((size_t)h << 21);

  const int t = threadIdx.x, wid = t >> 6, lane = t & 63;
  const int f = lane & 15;
  const int wr = wid >> 2, wc = wid & 3;
  const int swzg = (((lane >> 4) ^ ((f >> 1) & 3)) << 4);
  const int aoff = ((wr << 7) + f) * 64 + swzg;
  const int boff = 65536 + ((wc << 6) + f) * 64 + swzg;
  const int srow = t >> 2;
  const int scol = (((t & 3) ^ ((t >> 3) & 3)) << 3);
  const int sdst = wid << 10;

  f32x4 acc[8][4] = {};
  bf16x8 aR[8], bR[2];

  auto stageA = [&](int buf, int kh, int k0) {
    char* d = lds + buf * 32768 + kh * 16384 + sdst;
    const __hip_bfloat16* g = Ag + (size_t)(tm + srow) * 1024 + k0 + (kh << 5) + scol;
    gload16(g, d);
    gload16(g + 128 * 1024, d + 8192);
  };
  auto stageB = [&](int buf, int kh, int k0) {
    char* d = lds + 65536 + buf * 32768 + kh * 16384 + sdst;
    const __hip_bfloat16* g = Bg + (size_t)(tn + srow) * 1024 + k0 + (kh << 5) + scol;
    gload16(g, d);
    gload16(g + 128 * 1024, d + 8192);
  };

  stageA(0, 0, 0); stageB(0, 0, 0); stageA(0, 1, 0); stageB(0, 1, 0);
  VMW4();
  SBAR(); FEN();

  for (int kt = 0; kt < 15; ++kt) {
    const int buf = kt & 1, nbuf = buf ^ 1;
    const int bo = buf * 32768;
    const int nk0 = (kt + 1) << 6;
    // P1+P2 (kh0): stage A0',B0'; certify kh1(this tile) at end
#pragma unroll
    for (int mi = 0; mi < 8; ++mi) aR[mi] = *(const bf16x8*)(lds + bo + aoff + mi * 1024);
    bR[0] = *(const bf16x8*)(lds + bo + boff);
    bR[1] = *(const bf16x8*)(lds + bo + boff + 1024);
    stageA(nbuf, 0, nk0);
    PRIO1(); MFMA16(0); PRIO0();
    bR[0] = *(const bf16x8*)(lds + bo + boff + 2048);
    bR[1] = *(const bf16x8*)(lds + bo + boff + 3072);
    stageB(nbuf, 0, nk0);
    PRIO1(); MFMA16(2); PRIO0();
    VMW4();
    SBAR(); FEN();
    // P3+P4 (kh1): stage A1',B1'; certify kh0(next tile) at end
#pragma unroll
    for (int mi = 0; mi < 8; ++mi) aR[mi] = *(const bf16x8*)(lds + bo + 16384 + aoff + mi * 1024);
    bR[0] = *(const bf16x8*)(lds + bo + 16384 + boff);
    bR[1] = *(const bf16x8*)(lds + bo + 16384 + boff + 1024);
    stageA(nbuf, 1, nk0);
    PRIO1(); MFMA16(0); PRIO0();
    bR[0] = *(const bf16x8*)(lds + bo + 16384 + boff + 2048);
    bR[1] = *(const bf16x8*)(lds + bo + 16384 + boff + 3072);
    stageB(nbuf, 1, nk0);
    PRIO1(); MFMA16(2); PRIO0();
    VMW4();
    SBAR(); FEN();
  }
  { // epilogue: tile 15 in buf1
    const int bo = 32768;
#pragma unroll
    for (int mi = 0; mi < 8; ++mi) aR[mi] = *(const bf16x8*)(lds + bo + aoff + mi * 1024);
    bR[0] = *(const bf16x8*)(lds + bo + boff);
    bR[1] = *(const bf16x8*)(lds + bo + boff + 1024);
    PRIO1(); MFMA16(0); PRIO0();
    bR[0] = *(const bf16x8*)(lds + bo + boff + 2048);
    bR[1] = *(const bf16x8*)(lds + bo + boff + 3072);
    PRIO1(); MFMA16(2); PRIO0();
    VMW0();
    SBAR(); FEN();
#pragma unroll
    for (int mi = 0; mi < 8; ++mi) aR[mi] = *(const bf16x8*)(lds + bo + 16384 + aoff + mi * 1024);
    bR[0] = *(const bf16x8*)(lds + bo + 16384 + boff);
    bR[1] = *(const bf16x8*)(lds + bo + 16384 + boff + 1024);
    PRIO1(); MFMA16(0); PRIO0();
    bR[0] = *(const bf16x8*)(lds + bo + 16384 + boff + 2048);
    bR[1] = *(const bf16x8*)(lds + bo + 16384 + boff + 3072);
    PRIO1(); MFMA16(2); PRIO0();
  }

  float* Cc = attn + ((size_t)h << 22);
  const int rbase = tm + (wr << 7) + ((lane >> 4) << 2);
  const int cbase = tn + (wc << 6) + f;
#pragma unroll
  for (int mi = 0; mi < 8; ++mi)
#pragma unroll
    for (int i = 0; i < 4; ++i) {
      float* rp = Cc + ((size_t)(rbase + mi * 16 + i) << 11) + cbase;
#pragma unroll
      for (int ni = 0; ni < 4; ++ni) rp[ni * 16] = acc[mi][ni][i];
    }
}

// ---------------- context GEMM (K-split) ----------------
__global__ __launch_bounds__(256) void k_ctx(
    const __hip_bfloat16* __restrict__ vfT, const __hip_bfloat16* __restrict__ kfT,
    float* __restrict__ ctxp) {
  __shared__ __align__(16) __bf16 As[4096], Bs[4096];
  const int z = blockIdx.z, h = z >> 2, kc = z & 3;
  const int tn = blockIdx.y << 7;
  f32x4 acc[4][4];
  ZERO_ACC(acc);
  gemm_core(vfT + ((size_t)h << 18) + (kc << 9), kfT + ((size_t)h << 21) + (kc << 9),
            2048, 2048, 512, 0, tn, As, Bs, acc);
  float* Cp = ctxp + ((size_t)(kc * 8 + h) << 17);
  const int t = threadIdx.x, w = t >> 6, lane = t & 63;
  const int m_off = (w >> 1) << 6, n_off = (w & 1) << 6;
#pragma unroll
  for (int mi = 0; mi < 4; ++mi)
#pragma unroll
    for (int i = 0; i < 4; ++i) {
      const int row = m_off + mi * 16 + ((lane >> 4) << 2) + i;
#pragma unroll
      for (int ni = 0; ni < 4; ++ni) {
        const int col = tn + n_off + ni * 16 + (lane & 15);
        Cp[((size_t)row << 10) + col] = acc[mi][ni][i];
      }
    }
}

__global__ void k_ctxred(const float* __restrict__ ctxp, __hip_bfloat16* __restrict__ ctxT) {
  const int i = (blockIdx.x * 256 + threadIdx.x) * 4;
  f32x4 a = *(const f32x4*)(ctxp + i);
  f32x4 b = *(const f32x4*)(ctxp + i + 1048576);
  f32x4 c = *(const f32x4*)(ctxp + i + 2097152);
  f32x4 d = *(const f32x4*)(ctxp + i + 3145728);
  bf16x4 o;
#pragma unroll
  for (int j = 0; j < 4; ++j) o[j] = (__bf16)(a[j] + b[j] + c[j] + d[j]);
  *(bf16x4*)((__bf16*)ctxT + i) = o;
}

// ---------------- out GEMM (64-row tiles) + D_inv + scatter ----------------
__global__ __launch_bounds__(256) void k_out64(
    const __hip_bfloat16* __restrict__ qf, const __hip_bfloat16* __restrict__ ctxT,
    const float* __restrict__ dpart, float* __restrict__ outp) {
  __shared__ __align__(16) __bf16 As[2048], Bs[4096];
  __shared__ float dinv_s[64];
  const int h = blockIdx.z;
  const int tm = blockIdx.x << 6;            // 32 tiles of 64 rows
  const int t = threadIdx.x, w = t >> 6, lane = t & 63;
  if (t < 64) {
    float s = 0.f;
#pragma unroll
    for (int r = 0; r < 8; ++r) s += dpart[(((r << 3) + h) << 11) + tm + t];
    dinv_s[t] = 1.0f / s;
  }
  const int m_off = (w >> 1) << 5, n_off = (w & 1) << 6;
  const int r0 = t >> 2, kk = (t & 3) << 3;
  char* Asb = (char*)As + ((t >> 6) << 10);
  char* Bsb = (char*)Bs + ((t >> 6) << 10);
  const int frow = lane & 15, koff = (lane >> 4) << 3;
  const __hip_bfloat16* A = qf + ((size_t)h << 21);
  const __hip_bfloat16* B = ctxT + ((size_t)h << 17);
  f32x4 acc[2][4];
#pragma unroll
  for (int a_ = 0; a_ < 2; ++a_)
#pragma unroll
    for (int b_ = 0; b_ < 4; ++b_) acc[a_][b_] = (f32x4){0.f, 0.f, 0.f, 0.f};
  for (int k0 = 0; k0 < 1024; k0 += 32) {
    const __hip_bfloat16* Agp = A + (size_t)(tm + r0) * 1024 + (k0 + kk);
    const __hip_bfloat16* Bgp = B + (size_t)r0 * 1024 + (k0 + kk);
    gload16(Agp, Asb);
    gload16(Bgp, Bsb);
    gload16(Bgp + (size_t)64 * 1024, Bsb + 4096);
    __syncthreads();
    bf16x8 af[2], bfr[4];
#pragma unroll
    for (int mi = 0; mi < 2; ++mi)
      af[mi] = *(const bf16x8*)(As + ((m_off + mi * 16 + frow) << 5) + koff);
#pragma unroll
    for (int ni = 0; ni < 4; ++ni)
      bfr[ni] = *(const bf16x8*)(Bs + ((n_off + ni * 16 + frow) << 5) + koff);
#pragma unroll
    for (int mi = 0; mi < 2; ++mi)
#pragma unroll
      for (int ni = 0; ni < 4; ++ni)
        acc[mi][ni] = __builtin_amdgcn_mfma_f32_16x16x32_bf16(af[mi], bfr[ni], acc[mi][ni], 0, 0, 0);
    __syncthreads();
  }
#pragma unroll
  for (int mi = 0; mi < 2; ++mi)
#pragma unroll
    for (int i = 0; i < 4; ++i) {
      const int rl = m_off + mi * 16 + ((lane >> 4) << 2) + i;
      const int row = tm + rl;
      const float dv = dinv_s[rl];
#pragma unroll
      for (int ni = 0; ni < 4; ++ni) {
        const int col = n_off + ni * 16 + frow;
        const int rb = col >> 4, tt = col & 15;
        outp[(((size_t)(rb << 11) + row) << 7) + (h << 4) + tt] = acc[mi][ni][i] * dv;
      }
    }
}

// ---------------- launch ----------------
extern "C" void kernel_launch(void* const* d_in, const int* in_sizes, int n_in,
                              void* d_out, int out_size, void* d_ws, size_t ws_size,
                              hipStream_t stream) {
  const float* x    = (const float*)d_in[0];
  const float* Wq   = (const float*)d_in[1];
  const float* bq   = (const float*)d_in[2];
  const float* Wk   = (const float*)d_in[3];
  const float* bk   = (const float*)d_in[4];
  const float* Wv   = (const float*)d_in[5];
  const float* bv   = (const float*)d_in[6];
  const float* proj = (const float*)d_in[7];
  if (ws_size < WS_NEED) return;

  char* ws = (char*)d_ws;
  __hip_bfloat16* xb   = (__hip_bfloat16*)(ws + OFF_XB);
  __hip_bfloat16* Wcat = (__hip_bfloat16*)(ws + OFF_WCAT);
  __hip_bfloat16* Mq   = (__hip_bfloat16*)(ws + OFF_MQ);
  __hip_bfloat16* Mk   = (__hip_bfloat16*)(ws + OFF_MK);
  float* bcat = (float*)(ws + OFF_BCAT);
  float* bqf  = (float*)(ws + OFF_BQF);
  float* bkf  = (float*)(ws + OFF_BKF);
  float* Y    = (float*)(ws + OFF_Y);
  __hip_bfloat16* qf  = (__hip_bfloat16*)(ws + OFF_QF);
  __hip_bfloat16* kf  = (__hip_bfloat16*)(ws + OFF_KF);
  __hip_bfloat16* kfT = (__hip_bfloat16*)(ws + OFF_KFT);
  __hip_bfloat16* vfT = (__hip_bfloat16*)(ws + OFF_VFT);
  float* kpart  = (float*)(ws + OFF_KPART);
  float* kspart = (float*)(ws + OFF_KSPART);
  float* dpart  = (float*)(ws + OFF_DPART);
  float* ctxp   = (float*)(ws + OFF_CTXP);
  __hip_bfloat16* ctxT = (__hip_bfloat16*)(ws + OFF_CTXT);

  float* outp = (float*)d_out;
  float* attn = (float*)d_out + 2097152;

  static int attr_done = 0;
  if (!attr_done) {
    (void)hipFuncSetAttribute((const void*)k_attn8,
                              hipFuncAttributeMaxDynamicSharedMemorySize, 131072);
    attr_done = 1;
  }

  k_prep<<<dim3(2048), dim3(256), 0, stream>>>(x, Wq, bq, Wk, bk, Wv, bv, proj,
                                               xb, Wcat, bcat, Mq, Mk, bqf, bkf);
  k_proj<<<dim3(128, 3), dim3(256), 0, stream>>>(xb, Wcat, bcat, Y, vfT);
  k_dashk_max<<<dim3(128, 8), dim3(256), 0, stream>>>(xb, Mk, bkf, kpart);
  k_dashk_feat<<<dim3(128, 8), dim3(256), 0, stream>>>(xb, Mk, bkf, Y, kpart, kf, kfT, kspart);
  k_dashq<<<dim3(128, 8), dim3(256), 0, stream>>>(xb, Mq, bqf, Y, kspart, qf, dpart);
  k_attn8<<<dim3(512), dim3(512), 131072, stream>>>(qf, kf, attn);
  k_ctx<<<dim3(1, 8, 32), dim3(256), 0, stream>>>(vfT, kfT, ctxp);
  k_ctxred<<<dim3(1024), dim3(256), 0, stream>>>(ctxp, ctxT);
  k_out64<<<dim3(32, 1, 8), dim3(256), 0, stream>>>(qf, ctxT, dpart, outp);
}